// Round 13
// baseline (508.446 us; speedup 1.0000x reference)
//
#include <hip/hip_runtime.h>

#define NCLS 1000
#define NB 4096
#define PD 512
#define GBLK 63
#define KSTRIDE 1024

typedef __attribute__((ext_vector_type(8))) short bf16x8;
typedef __attribute__((ext_vector_type(4))) float f32x4;
typedef __attribute__((ext_vector_type(16))) float f32x16;

__device__ __forceinline__ ushort f2bf(float x) {
  union { float f; unsigned u; } c; c.f = x;
  unsigned r = c.u + 0x7FFFu + ((c.u >> 16) & 1u);
  return (ushort)(r >> 16);
}
__device__ __forceinline__ float bf2f(ushort h) {
  union { unsigned u; float f; } c; c.u = ((unsigned)h) << 16; return c.f;
}

// ================= prep_all: classprep(b0) | zero S | weight splits | feat conv =================
// blocks: 0 classprep | [1,3908) zero S | [3908,8444) weight splits | [8444,20732) feat conv
__global__ __launch_bounds__(256) void prep_all(
    const int* __restrict__ target, int* __restrict__ cnt_g, int* __restrict__ offs_g,
    int* __restrict__ rank, int* __restrict__ clss, int* __restrict__ ibuf,
    float* __restrict__ S,
    const float* __restrict__ Wt, ushort* __restrict__ Wthi, ushort* __restrict__ Wtlo,
    const float* __restrict__ Ws, ushort* __restrict__ Wshi, ushort* __restrict__ Wslo,
    const float* __restrict__ wt, ushort* __restrict__ wthi, ushort* __restrict__ wtlo,
    const float* __restrict__ ws, ushort* __restrict__ wshi, ushort* __restrict__ wslo,
    const float* __restrict__ ft, ushort* __restrict__ ftb,
    const float* __restrict__ fs, ushort* __restrict__ fsb) {
  int b = blockIdx.x;
  int t = threadIdx.x;
  if (b == 0) {
    // ---- classprep with 256 threads ----
    __shared__ int cnt_s[1024];
    __shared__ int tsum[256];
    for (int i = t; i < 1024; i += 256) cnt_s[i] = 0;
    ibuf[t] = 0;
    __syncthreads();
    int tg[16];
#pragma unroll
    for (int q = 0; q < 16; ++q) {
      tg[q] = target[t + 256 * q];
      atomicAdd(&cnt_s[tg[q]], 1);
    }
    __syncthreads();
    int c0 = cnt_s[4 * t], c1 = cnt_s[4 * t + 1], c2 = cnt_s[4 * t + 2], c3 = cnt_s[4 * t + 3];
    int local = c0 + c1 + c2 + c3;
    tsum[t] = local;
    __syncthreads();
    for (int d = 1; d < 256; d <<= 1) {
      int v2 = (t >= d) ? tsum[t - d] : 0;
      __syncthreads();
      tsum[t] += v2;
      __syncthreads();
    }
    int base = tsum[t] - local;
    int o0 = base, o1 = base + c0, o2 = o1 + c1, o3 = o2 + c2;
    if (4 * t < NCLS)     { cnt_g[4 * t] = c0;     offs_g[4 * t] = o0; }
    if (4 * t + 1 < NCLS) { cnt_g[4 * t + 1] = c1; offs_g[4 * t + 1] = o1; }
    if (4 * t + 2 < NCLS) { cnt_g[4 * t + 2] = c2; offs_g[4 * t + 2] = o2; }
    if (4 * t + 3 < NCLS) { cnt_g[4 * t + 3] = c3; offs_g[4 * t + 3] = o3; }
    cnt_s[4 * t] = o0; cnt_s[4 * t + 1] = o1; cnt_s[4 * t + 2] = o2; cnt_s[4 * t + 3] = o3;
    __syncthreads();
#pragma unroll
    for (int q = 0; q < 16; ++q) {
      int i = t + 256 * q;
      int pos = atomicAdd(&cnt_s[tg[q]], 1);
      rank[i] = pos;
      clss[pos] = tg[q];
    }
    return;
  }
  if (b < 3908) {
    int i = (b - 1) * 256 + t;
    if (i < NCLS * NCLS) S[i] = 0.f;
    return;
  }
  if (b >= 8444) {
    int idx = (b - 8444) * 256 + t;
    const float* src; ushort* dst;
    if (idx < 2097152) { src = ft; dst = ftb; }
    else { idx -= 2097152; src = fs; dst = fsb; }
    float4 v = reinterpret_cast<const float4*>(src)[idx];
    ushort4 h;
    h.x = f2bf(v.x); h.y = f2bf(v.y); h.z = f2bf(v.z); h.w = f2bf(v.w);
    reinterpret_cast<ushort4*>(dst)[idx] = h;
    return;
  }
  int idx = (b - 3908) * 256 + t;
  const float* src; ushort* hi; ushort* lo;
  if (idx < 262144) { src = Wt; hi = Wthi; lo = Wtlo; }
  else {
    idx -= 262144;
    if (idx < 131072) { src = Ws; hi = Wshi; lo = Wslo; }
    else {
      idx -= 131072;
      if (idx < 512000) { src = wt; hi = wthi; lo = wtlo; }
      else { idx -= 512000; src = ws; hi = wshi; lo = wslo; }
    }
  }
  float4 v = reinterpret_cast<const float4*>(src)[idx];
  float vv[4] = {v.x, v.y, v.z, v.w};
  ushort h[4], l[4];
#pragma unroll
  for (int j = 0; j < 4; ++j) {
    h[j] = f2bf(vv[j]);
    l[j] = f2bf(vv[j] - bf2f(h[j]));
  }
  ushort4 h4; h4.x = h[0]; h4.y = h[1]; h4.z = h[2]; h4.w = h[3];
  ushort4 l4; l4.x = l[0]; l4.y = l[1]; l4.z = l[2]; l4.w = l[3];
  reinterpret_cast<ushort4*>(hi)[idx] = h4;
  reinterpret_cast<ushort4*>(lo)[idx] = l4;
}

// ---------------- split-bf16 MFMA per-wave 32x32 tile ----------------
__device__ __forceinline__ void gemm_split_wave(
    const ushort* __restrict__ Ahi, const ushort* __restrict__ Alo,
    const ushort* __restrict__ Bhi, const ushort* __restrict__ Blo,
    float* __restrict__ C, int M, int N, int K,
    const float* __restrict__ rn, const float* __restrict__ cn, int mode,
    int rA, int rB, int lane) {
  int lr = lane & 15, lk = (lane >> 4) << 3;
  bf16x8 zb = {0, 0, 0, 0, 0, 0, 0, 0};
  f32x4 z4 = {0.f, 0.f, 0.f, 0.f};
  f32x4 acc[2][2];
#pragma unroll
  for (int i = 0; i < 2; ++i)
#pragma unroll
    for (int j = 0; j < 2; ++j) acc[i][j] = z4;
  for (int kb = 0; kb < K; kb += 32) {
    bf16x8 ah[2], al[2], bh[2], bl[2];
#pragma unroll
    for (int f = 0; f < 2; ++f) {
      int ra = rA + f * 16 + lr;
      if (ra < M) {
        size_t o = (size_t)ra * K + kb + lk;
        ah[f] = *reinterpret_cast<const bf16x8*>(Ahi + o);
        al[f] = *reinterpret_cast<const bf16x8*>(Alo + o);
      } else { ah[f] = zb; al[f] = zb; }
      int rb = rB + f * 16 + lr;
      if (rb < N) {
        size_t o = (size_t)rb * K + kb + lk;
        bh[f] = *reinterpret_cast<const bf16x8*>(Bhi + o);
        bl[f] = *reinterpret_cast<const bf16x8*>(Blo + o);
      } else { bh[f] = zb; bl[f] = zb; }
    }
#pragma unroll
    for (int i = 0; i < 2; ++i)
#pragma unroll
      for (int j = 0; j < 2; ++j) {
        acc[i][j] = __builtin_amdgcn_mfma_f32_16x16x32_bf16(ah[i], bh[j], acc[i][j], 0, 0, 0);
        acc[i][j] = __builtin_amdgcn_mfma_f32_16x16x32_bf16(ah[i], bl[j], acc[i][j], 0, 0, 0);
        acc[i][j] = __builtin_amdgcn_mfma_f32_16x16x32_bf16(al[i], bh[j], acc[i][j], 0, 0, 0);
      }
  }
#pragma unroll
  for (int i = 0; i < 2; ++i)
#pragma unroll
    for (int j = 0; j < 2; ++j)
#pragma unroll
      for (int r = 0; r < 4; ++r) {
        int m = rA + i * 16 + ((lane >> 4) << 2) + r;
        int n = rB + j * 16 + lr;
        if (m < M && n < N) {
          float vv = acc[i][j][r];
          if (mode == 1) vv = fmaxf(rn[m] + cn[n] - 2.f * vv, 0.f);
          C[(size_t)m * N + n] = vv;
        }
      }
}

// ================= gemm_stage2 (512 thr): weight projections | feat GEMMs =================
// blocks: [0,64) wtp | [64,128) wsp | [128,384) feat_t | [384,640) feat_s
__global__ __launch_bounds__(512) void gemm_stage2(
    const ushort* __restrict__ wthi, const ushort* __restrict__ wtlo,
    const ushort* __restrict__ Wthi, const ushort* __restrict__ Wtlo, float* __restrict__ wtp,
    const ushort* __restrict__ wshi, const ushort* __restrict__ wslo,
    const ushort* __restrict__ Wshi, const ushort* __restrict__ Wslo, float* __restrict__ wsp,
    const ushort* __restrict__ ftb, ushort* __restrict__ ftg,
    const ushort* __restrict__ fsb, ushort* __restrict__ fsg,
    const int* __restrict__ rank) {
  int b = blockIdx.x;
  int tid = threadIdx.x;
  int lane = tid & 63, wv = tid >> 6;
  if (b < 128) {
    // split-bf16 weight projections, 64x128 tile, 8 waves (2x4)
    int z = (b >= 64);
    int local = b - (z ? 64 : 0);
    int m0 = (local >> 2) * 64, n0 = (local & 3) * 128;
    int rA = m0 + (wv >> 2) * 32, rB = n0 + (wv & 3) * 32;
    gemm_split_wave(z ? wshi : wthi, z ? wslo : wtlo,
                    z ? Wshi : Wthi, z ? Wslo : Wtlo,
                    z ? wsp : wtp, NCLS, PD, z ? 1024 : 2048,
                    nullptr, nullptr, 0, rA, rB, lane);
    return;
  }
  // feat GEMMs: bf16 A, 64x128 tile, 8 waves
  int z = (b >= 384);
  int local = b - (z ? 384 : 128);
  const ushort* A = z ? fsb : ftb;
  const ushort* B = z ? Wshi : Wthi;
  ushort* G = z ? fsg : ftg;
  int K = z ? 1024 : 2048;
  __shared__ int rk[64];
  int wi = wv >> 2, wj = wv & 3;
  int m0 = (local >> 2) * 64, n0 = (local & 3) * 128;
  if (tid < 64) rk[tid] = rank[m0 + tid];
  int lr = lane & 15, lk = (lane >> 4) << 3;
  const ushort* pa0 = A + (size_t)(m0 + wi * 32 + lr) * K + lk;
  const ushort* pa1 = pa0 + (size_t)16 * K;
  const ushort* pb0 = B + (size_t)(n0 + wj * 32 + lr) * K + lk;
  const ushort* pb1 = pb0 + (size_t)16 * K;
  f32x4 z4 = {0.f, 0.f, 0.f, 0.f};
  f32x4 a00 = z4, a01 = z4, a10 = z4, a11 = z4;
#pragma unroll 2
  for (int kb = 0; kb < K; kb += 32) {
    bf16x8 a0 = *reinterpret_cast<const bf16x8*>(pa0 + kb);
    bf16x8 a1 = *reinterpret_cast<const bf16x8*>(pa1 + kb);
    bf16x8 b0 = *reinterpret_cast<const bf16x8*>(pb0 + kb);
    bf16x8 b1 = *reinterpret_cast<const bf16x8*>(pb1 + kb);
    a00 = __builtin_amdgcn_mfma_f32_16x16x32_bf16(a0, b0, a00, 0, 0, 0);
    a01 = __builtin_amdgcn_mfma_f32_16x16x32_bf16(a0, b1, a01, 0, 0, 0);
    a10 = __builtin_amdgcn_mfma_f32_16x16x32_bf16(a1, b0, a10, 0, 0, 0);
    a11 = __builtin_amdgcn_mfma_f32_16x16x32_bf16(a1, b1, a11, 0, 0, 0);
  }
  __syncthreads();
  f32x4 acc[2][2] = {{a00, a01}, {a10, a11}};
#pragma unroll
  for (int i = 0; i < 2; ++i)
#pragma unroll
    for (int j = 0; j < 2; ++j)
#pragma unroll
      for (int r = 0; r < 4; ++r) {
        int rloc = wi * 32 + i * 16 + ((lane >> 4) << 2) + r;
        int n = n0 + wj * 32 + j * 16 + lr;
        G[(size_t)rk[rloc] * PD + n] = f2bf(acc[i][j][r]);
      }
}

// ================= norms_all (256 thr): class pairs | normsplit | bf16 norms =================
// blocks: [0,1000) pairs | [1000,3000) normsplit | [3000,4024) norms
__global__ __launch_bounds__(256) void norms_all(
    const ushort* __restrict__ ftg, const ushort* __restrict__ fsg,
    float* __restrict__ ftns, float* __restrict__ fsns,
    float* __restrict__ ftns2, float* __restrict__ fsns2,
    const int* __restrict__ offs, const int* __restrict__ cnt,
    float* __restrict__ s_tt, float* __restrict__ s_ss,
    const float* __restrict__ wtp, const float* __restrict__ wsp,
    float* __restrict__ wtn, float* __restrict__ wsn,
    ushort* __restrict__ wtphi, ushort* __restrict__ wtplo,
    ushort* __restrict__ wsphi, ushort* __restrict__ wsplo) {
  int b = blockIdx.x;
  int lane = threadIdx.x & 63, wave = threadIdx.x >> 6;
  if (b < 1000) {
    int k = b;
    int c = cnt[k];
    if (c == 0) {
      if (threadIdx.x == 0) { s_tt[k] = 0.f; s_ss[k] = 0.f; }
      return;
    }
    int base = offs[k];
    int tot = c * (c - 1);
    float sumt = 0.f, sums = 0.f;
    for (int p = wave; p < tot; p += 4) {
      int i = p / (c - 1), q = p - i * (c - 1);
      int j = q + (q >= i);
      bf16x8 ta = *reinterpret_cast<const bf16x8*>(ftg + (size_t)(base + i) * PD + lane * 8);
      bf16x8 tb = *reinterpret_cast<const bf16x8*>(ftg + (size_t)(base + j) * PD + lane * 8);
      bf16x8 sa = *reinterpret_cast<const bf16x8*>(fsg + (size_t)(base + i) * PD + lane * 8);
      bf16x8 sb = *reinterpret_cast<const bf16x8*>(fsg + (size_t)(base + j) * PD + lane * 8);
      float dt = 0.f, ds = 0.f;
#pragma unroll
      for (int e = 0; e < 8; ++e) {
        float d1 = bf2f((ushort)ta[e]) - bf2f((ushort)tb[e]); dt += d1 * d1;
        float d2 = bf2f((ushort)sa[e]) - bf2f((ushort)sb[e]); ds += d2 * d2;
      }
#pragma unroll
      for (int off = 32; off; off >>= 1) { dt += __shfl_down(dt, off); ds += __shfl_down(ds, off); }
      if (lane == 0) { sumt += __expf(-0.5f * dt); sums += __expf(-0.5f * ds); }
    }
    __shared__ float rt[4], rs[4];
    if (lane == 0) { rt[wave] = sumt; rs[wave] = sums; }
    __syncthreads();
    if (threadIdx.x == 0) {
      s_tt[k] = (float)c + rt[0] + rt[1] + rt[2] + rt[3];
      s_ss[k] = (float)c + rs[0] + rs[1] + rs[2] + rs[3];
    }
    return;
  }
  if (b < 3000) {
    int bb = b - 1000, t = threadIdx.x;
    int row = (bb < NCLS) ? bb : bb - NCLS;
    const float* src = (bb < NCLS) ? wtp : wsp;
    ushort* hi = (bb < NCLS) ? wtphi : wsphi;
    ushort* lo = (bb < NCLS) ? wtplo : wsplo;
    float* nrm = (bb < NCLS) ? wtn : wsn;
    float2 v = reinterpret_cast<const float2*>(src + (size_t)row * PD)[t];
    ushort h0 = f2bf(v.x), h1 = f2bf(v.y);
    ushort l0 = f2bf(v.x - bf2f(h0)), l1 = f2bf(v.y - bf2f(h1));
    ushort2 h2; h2.x = h0; h2.y = h1;
    ushort2 l2; l2.x = l0; l2.y = l1;
    reinterpret_cast<ushort2*>(hi + (size_t)row * PD)[t] = h2;
    reinterpret_cast<ushort2*>(lo + (size_t)row * PD)[t] = l2;
    float s = v.x * v.x + v.y * v.y;
    __shared__ float red[256];
    red[t] = s;
    __syncthreads();
    for (int st = 128; st > 0; st >>= 1) {
      if (t < st) red[t] += red[t + st];
      __syncthreads();
    }
    if (t == 0) nrm[row] = red[0];
    return;
  }
  int r = (b - 3000) * 4 + wave;
  bf16x8 a = *reinterpret_cast<const bf16x8*>(ftg + (size_t)r * PD + lane * 8);
  bf16x8 bb2 = *reinterpret_cast<const bf16x8*>(fsg + (size_t)r * PD + lane * 8);
  float st = 0.f, ss = 0.f;
#pragma unroll
  for (int e = 0; e < 8; ++e) {
    float x = bf2f((ushort)a[e]); st += x * x;
    float y = bf2f((ushort)bb2[e]); ss += y * y;
  }
  float stp = (lane < 16) ? st : 0.f;
  float ssp = (lane < 16) ? ss : 0.f;
#pragma unroll
  for (int off = 32; off; off >>= 1) {
    st += __shfl_down(st, off); ss += __shfl_down(ss, off);
    stp += __shfl_down(stp, off); ssp += __shfl_down(ssp, off);
  }
  if (lane == 0) { ftns[r] = st; fsns[r] = ss; ftns2[r] = stp; fsns2[r] = ssp; }
}

// ================= cw_sts (256 thr): C_weight GEMM | sts_mfma =================
// blocks: [0,256) splitC | [256,4352) sts
__global__ __launch_bounds__(256) void cw_sts(
    const ushort* __restrict__ wtphi, const ushort* __restrict__ wtplo,
    const ushort* __restrict__ wsphi, const ushort* __restrict__ wsplo,
    float* __restrict__ Cm, const float* __restrict__ wtn, const float* __restrict__ wsn,
    const ushort* __restrict__ ftg, const ushort* __restrict__ fsg,
    const int* __restrict__ clss, const float* __restrict__ ftns,
    const float* __restrict__ fsns, const float* __restrict__ ftns2,
    const float* __restrict__ fsns2, float* __restrict__ S) {
  int b = blockIdx.x;
  int tid = threadIdx.x;
  int lane = tid & 63, wv = tid >> 6;
  if (b < 256) {
    int m0 = (b >> 4) * 64, n0 = (b & 15) * 64;
    int rA = m0 + (wv >> 1) * 32, rB = n0 + (wv & 1) * 32;
    gemm_split_wave(wtphi, wtplo, wsphi, wsplo, Cm, NCLS, NCLS, PD,
                    wtn, wsn, 1, rA, rB, lane);
    return;
  }
  int local = b - 256;
  int i0 = (local >> 6) * 64, j0 = (local & 63) * 64;
  __shared__ float tbl[64 * 64];
  __shared__ int rslot[64], cslot[64], rcls[64], ccls[64];
  __shared__ float rns[64], cns[64], prns[64], pcns[64];
  __shared__ int nrs_s, ncs_s;
  int wi = wv >> 1, wj = wv & 1;

  if (tid < 64) {
    int myc = clss[i0 + tid];
    rns[tid] = ftns[i0 + tid]; prns[tid] = ftns2[i0 + tid];
    int flag = (tid > 0) && (myc != clss[i0 + tid - 1]);
    unsigned long long mask = __ballot(flag);
    int slot = __popcll(mask & ((1ull << tid) - 1ull));
    rslot[tid] = slot;
    if (flag || tid == 0) rcls[slot] = myc;
    if (tid == 63) nrs_s = slot + 1;
  } else if (tid < 128) {
    int t = tid - 64;
    int myc = clss[j0 + t];
    cns[t] = fsns[j0 + t]; pcns[t] = fsns2[j0 + t];
    int flag = (t > 0) && (myc != clss[j0 + t - 1]);
    unsigned long long mask = __ballot(flag);
    int slot = __popcll(mask & ((1ull << t) - 1ull));
    cslot[t] = slot;
    if (flag || t == 0) ccls[slot] = myc;
    if (t == 63) ncs_s = slot + 1;
  }
  for (int t = tid; t < 64 * 64; t += 256) tbl[t] = 0.f;
  __syncthreads();

  int r31 = lane & 31, kg = (lane >> 5) << 3;
  const ushort* pa = ftg + (size_t)(i0 + wi * 32 + r31) * PD + kg;
  const ushort* pb = fsg + (size_t)(j0 + wj * 32 + r31) * PD + kg;
  f32x16 acc0, acc1;
#pragma unroll
  for (int r = 0; r < 16; ++r) { acc0[r] = 0.f; acc1[r] = 0.f; }
#pragma unroll
  for (int kb = 0; kb < 128; kb += 32) {
    bf16x8 a0 = *reinterpret_cast<const bf16x8*>(pa + kb);
    bf16x8 b0 = *reinterpret_cast<const bf16x8*>(pb + kb);
    bf16x8 a1 = *reinterpret_cast<const bf16x8*>(pa + kb + 16);
    bf16x8 b1 = *reinterpret_cast<const bf16x8*>(pb + kb + 16);
    acc0 = __builtin_amdgcn_mfma_f32_32x32x16_bf16(a0, b0, acc0, 0, 0, 0);
    acc1 = __builtin_amdgcn_mfma_f32_32x32x16_bf16(a1, b1, acc1, 0, 0, 0);
  }
  int rbase = 4 * (lane >> 5);
  int cloc = wj * 32 + r31;
  float minv = 1e30f;
#pragma unroll
  for (int r = 0; r < 16; ++r) {
    int rloc = wi * 32 + rbase + (r & 3) + 8 * (r >> 2);
    float d = prns[rloc] + pcns[cloc] - 2.f * (acc0[r] + acc1[r]);
    minv = fminf(minv, d);
  }
  bool skip = __all(minv > 300.f);
  if (!skip) {
#pragma unroll
    for (int kb = 128; kb < PD; kb += 32) {
      bf16x8 a0 = *reinterpret_cast<const bf16x8*>(pa + kb);
      bf16x8 b0 = *reinterpret_cast<const bf16x8*>(pb + kb);
      bf16x8 a1 = *reinterpret_cast<const bf16x8*>(pa + kb + 16);
      bf16x8 b1 = *reinterpret_cast<const bf16x8*>(pb + kb + 16);
      acc0 = __builtin_amdgcn_mfma_f32_32x32x16_bf16(a0, b0, acc0, 0, 0, 0);
      acc1 = __builtin_amdgcn_mfma_f32_32x32x16_bf16(a1, b1, acc1, 0, 0, 0);
    }
  }
  __syncthreads();

  if (!skip) {
    int cs = cslot[cloc];
    float run = 0.f;
    int cur = rslot[wi * 32 + rbase];
#pragma unroll
    for (int r = 0; r < 16; ++r) {
      int rloc = wi * 32 + rbase + (r & 3) + 8 * (r >> 2);
      float d = fmaxf(rns[rloc] + cns[cloc] - 2.f * (acc0[r] + acc1[r]), 0.f);
      float e = __expf(-0.5f * d);
      int s = rslot[rloc];
      if (s != cur) {
        if (run != 0.f) atomicAdd(&tbl[cur * 64 + cs], run);
        run = 0.f; cur = s;
      }
      run += e;
    }
    if (run != 0.f) atomicAdd(&tbl[cur * 64 + cs], run);
  }
  __syncthreads();
  int NR = nrs_s, NC = ncs_s;
  for (int t = tid; t < NR * NC; t += 256) {
    int r = t / NC, c2 = t - r * NC;
    float vs = tbl[r * 64 + c2];
    if (vs != 0.f) atomicAdd(&S[(size_t)rcls[r] * NCLS + ccls[c2]], vs);
  }
}

// ================= combine =================
__global__ __launch_bounds__(256) void combine(
    float* __restrict__ C, const float* __restrict__ s_tt,
    const float* __restrict__ s_ss, const float* __restrict__ S,
    const int* __restrict__ cnt, float* __restrict__ Km, float* __restrict__ KmT) {
  __shared__ float tile[64][65];
  int tid = threadIdx.x;
  int k0 = (blockIdx.x >> 4) * 64, l0 = (blockIdx.x & 15) * 64;
  int tx = tid & 63, ty = tid >> 6;
#pragma unroll
  for (int r = 0; r < 16; ++r) {
    int k = k0 + ty * 16 + r, l = l0 + tx;
    float val = 0.f;
    if (k < NCLS && l < NCLS) {
      float cw = C[(size_t)k * NCLS + l];
      int ck = cnt[k], cl = cnt[l];
      float mmd = 0.f;
      if (ck > 0 && cl > 0) {
        float fk = (float)ck, fl = (float)cl;
        mmd = s_tt[k] / (fk * fk) + s_ss[l] / (fl * fl) - 2.f * S[(size_t)k * NCLS + l] / (fk * fl);
      }
      float c = cw - 0.1f * mmd;
      C[(size_t)k * NCLS + l] = c;
      val = __expf(-10.f * c);
    }
    Km[(size_t)k * KSTRIDE + l] = val;
    tile[ty * 16 + r][tx] = val;
  }
  __syncthreads();
#pragma unroll
  for (int r = 0; r < 16; ++r) {
    int l = l0 + ty * 16 + r, k = k0 + tx;
    KmT[(size_t)l * KSTRIDE + k] = tile[tx][ty * 16 + r];
  }
}

// ================= persistent Sinkhorn (round-7 proven) =================
__global__ __launch_bounds__(256, 1) void sinkhorn7(
    const float* __restrict__ Km, const float* __restrict__ KmT,
    const float* __restrict__ C, float* __restrict__ u, float* __restrict__ v,
    int* __restrict__ ibuf, float* __restrict__ out) {
  const int tid = threadIdx.x, bid = blockIdx.x;
  const int lane = tid & 63, wave = tid >> 6;
  const float ab = 1.f / (float)NCLS;
  const int r0 = bid * 16 + wave * 4;
  int* arr = ibuf;
  int* gen8 = ibuf + 128;
  __shared__ int any_s, bflag_s;

  float km[4][16], kt[4][16];
#pragma unroll
  for (int r = 0; r < 4; ++r) {
    const float* pm = Km + (size_t)(r0 + r) * KSTRIDE + lane;
    const float* pt = KmT + (size_t)(r0 + r) * KSTRIDE + lane;
#pragma unroll
    for (int m = 0; m < 16; ++m) { km[r][m] = pm[64 * m]; kt[r][m] = pt[64 * m]; }
  }

  if (bid == 0) {
    for (int i = tid; i < 1024; i += 256) {
      __hip_atomic_store(&u[i], (i < NCLS) ? ab : 0.f, __ATOMIC_RELAXED, __HIP_MEMORY_SCOPE_AGENT);
      __hip_atomic_store(&v[i], 0.f, __ATOMIC_RELAXED, __HIP_MEMORY_SCOPE_AGENT);
    }
    if (tid == 0) __hip_atomic_store(out, 0.f, __ATOMIC_RELAXED, __HIP_MEMORY_SCOPE_AGENT);
  }
  if (tid == 0) { any_s = 0; bflag_s = 0; }

  int ph = 0;
  auto bar = [&](int useflag) -> int {
    __syncthreads();
    ++ph;
    if (tid == 0) {
      int f = useflag ? bflag_s : 0;
      __hip_atomic_store(&arr[bid], (ph << 1) | f, __ATOMIC_RELEASE, __HIP_MEMORY_SCOPE_AGENT);
    }
    if (bid == 0) {
      int f = 0;
      if (tid < GBLK) {
        int val;
        while (((val = __hip_atomic_load(&arr[tid], __ATOMIC_RELAXED, __HIP_MEMORY_SCOPE_AGENT)) >> 1) < ph)
          __builtin_amdgcn_s_sleep(1);
        f = val & 1;
      }
      unsigned long long m = __ballot(f);
      if (tid == 0) any_s = (m != 0ull) ? 1 : 0;
      __syncthreads();
      int a = any_s;
      if (tid < 8)
        __hip_atomic_store(&gen8[tid], (ph << 1) | a, __ATOMIC_RELEASE, __HIP_MEMORY_SCOPE_AGENT);
      return a;
    } else {
      if (tid == 0) {
        int g;
        while (((g = __hip_atomic_load(&gen8[bid & 7], __ATOMIC_RELAXED, __HIP_MEMORY_SCOPE_AGENT)) >> 1) < ph)
          __builtin_amdgcn_s_sleep(1);
        any_s = g & 1;
      }
      __syncthreads();
      return any_s;
    }
  };

  bar(0);

  float up[4], ucur[4], vv[16], s[4];
#pragma unroll
  for (int r = 0; r < 4; ++r) { up[r] = ab; ucur[r] = ab; }

  for (int it = 0; it < 1000; ++it) {
    float uu[16];
#pragma unroll
    for (int m = 0; m < 16; ++m)
      uu[m] = __hip_atomic_load(&u[lane + 64 * m], __ATOMIC_RELAXED, __HIP_MEMORY_SCOPE_AGENT);
#pragma unroll
    for (int r = 0; r < 4; ++r) {
      float acc = 0.f;
#pragma unroll
      for (int m = 0; m < 16; ++m) acc += kt[r][m] * uu[m];
#pragma unroll
      for (int o = 32; o; o >>= 1) acc += __shfl_down(acc, o);
      s[r] = acc;
    }
    if (lane == 0) {
#pragma unroll
      for (int r = 0; r < 4; ++r) {
        float val = (r0 + r < NCLS) ? ab / s[r] : 0.f;
        __hip_atomic_store(&v[r0 + r], val, __ATOMIC_RELAXED, __HIP_MEMORY_SCOPE_AGENT);
      }
    }
    bar(0);

#pragma unroll
    for (int m = 0; m < 16; ++m)
      vv[m] = __hip_atomic_load(&v[lane + 64 * m], __ATOMIC_RELAXED, __HIP_MEMORY_SCOPE_AGENT);
#pragma unroll
    for (int r = 0; r < 4; ++r) {
      float acc = 0.f;
#pragma unroll
      for (int m = 0; m < 16; ++m) acc += km[r][m] * vv[m];
#pragma unroll
      for (int o = 32; o; o >>= 1) acc += __shfl_down(acc, o);
      s[r] = acc;
    }
#pragma unroll
    for (int r = 0; r < 4; ++r) {
      float sv = __shfl(s[r], 0);
      float val = (r0 + r < NCLS) ? ab / sv : 0.f;
      ucur[r] = val;
      if (lane == 0)
        __hip_atomic_store(&u[r0 + r], val, __ATOMIC_RELAXED, __HIP_MEMORY_SCOPE_AGENT);
    }
    int isC = ((it & 7) == 7);
    if (isC) {
      if (lane == 0) {
        bool nc = false;
#pragma unroll
        for (int r = 0; r < 4; ++r)
          if (r0 + r < NCLS && fabsf(ucur[r] - up[r]) > 5e-4f * ucur[r]) nc = true;
        if (nc) bflag_s = 1;
      }
#pragma unroll
      for (int r = 0; r < 4; ++r) up[r] = ucur[r];
    }
    int any = bar(isC);
    if (isC) {
      if (!any) break;
      if (tid == 0) bflag_s = 0;
    }
  }

  float part = 0.f;
#pragma unroll
  for (int r = 0; r < 4; ++r) {
    if (r0 + r < NCLS) {
      const float* cr = C + (size_t)(r0 + r) * NCLS;
      float acc = 0.f;
#pragma unroll
      for (int m = 0; m < 16; ++m)
        acc += km[r][m] * vv[m] * cr[lane + 64 * m];
#pragma unroll
      for (int o = 32; o; o >>= 1) acc += __shfl_down(acc, o);
      if (lane == 0) part += ucur[r] * acc;
    }
  }
  __shared__ float pr[4];
  if (lane == 0) pr[wave] = part;
  __syncthreads();
  if (tid == 0) atomicAdd(out, pr[0] + pr[1] + pr[2] + pr[3]);
}

// ================= host launch =================
extern "C" void kernel_launch(void* const* d_in, const int* in_sizes, int n_in,
                              void* d_out, int out_size, void* d_ws, size_t ws_size,
                              hipStream_t stream) {
  const float* feat_s = (const float*)d_in[0];  // 4096 x 1024
  const float* feat_t = (const float*)d_in[1];  // 4096 x 2048
  const float* w_s = (const float*)d_in[2];     // 1000 x 1024
  const float* w_t = (const float*)d_in[3];     // 1000 x 2048
  const float* Wt = (const float*)d_in[4];      // 512 x 2048
  const float* Ws = (const float*)d_in[5];      // 512 x 1024
  const int* target = (const int*)d_in[6];      // 4096
  float* out = (float*)d_out;

  char* base = (char*)d_ws;
  size_t off = 0;
  auto alloc = [&](size_t bytes) -> void* {
    void* p = base + off;
    off += (bytes + 255) & ~(size_t)255;
    return p;
  };
  ushort* Wthi = (ushort*)alloc((size_t)512 * 2048 * 2);
  ushort* Wtlo = (ushort*)alloc((size_t)512 * 2048 * 2);
  ushort* Wshi = (ushort*)alloc((size_t)512 * 1024 * 2);
  ushort* Wslo = (ushort*)alloc((size_t)512 * 1024 * 2);
  ushort* wthi = (ushort*)alloc((size_t)NCLS * 2048 * 2);
  ushort* wtlo = (ushort*)alloc((size_t)NCLS * 2048 * 2);
  ushort* wshi = (ushort*)alloc((size_t)NCLS * 1024 * 2);
  ushort* wslo = (ushort*)alloc((size_t)NCLS * 1024 * 2);
  ushort* ftb  = (ushort*)alloc((size_t)NB * 2048 * 2);
  ushort* fsb  = (ushort*)alloc((size_t)NB * 1024 * 2);
  float* wtp   = (float*)alloc((size_t)NCLS * PD * 4);
  float* wsp   = (float*)alloc((size_t)NCLS * PD * 4);
  ushort* wtphi = (ushort*)alloc((size_t)NCLS * PD * 2);
  ushort* wtplo = (ushort*)alloc((size_t)NCLS * PD * 2);
  ushort* wsphi = (ushort*)alloc((size_t)NCLS * PD * 2);
  ushort* wsplo = (ushort*)alloc((size_t)NCLS * PD * 2);
  float* wtn   = (float*)alloc(NCLS * 4);
  float* wsn   = (float*)alloc(NCLS * 4);
  ushort* ftg  = (ushort*)alloc((size_t)NB * PD * 2);
  ushort* fsg  = (ushort*)alloc((size_t)NB * PD * 2);
  float* ftns  = (float*)alloc(NB * 4);
  float* fsns  = (float*)alloc(NB * 4);
  float* ftns2 = (float*)alloc(NB * 4);
  float* fsns2 = (float*)alloc(NB * 4);
  int* cnt     = (int*)alloc(NCLS * 4);
  int* offs    = (int*)alloc(NCLS * 4);
  int* rank    = (int*)alloc(NB * 4);
  int* clss    = (int*)alloc(NB * 4);
  float* s_tt  = (float*)alloc(NCLS * 4);
  float* s_ss  = (float*)alloc(NCLS * 4);
  float* S     = (float*)alloc((size_t)NCLS * NCLS * 4);
  float* Cm    = (float*)alloc((size_t)NCLS * NCLS * 4);
  float* Km    = (float*)alloc((size_t)KSTRIDE * KSTRIDE * 4);
  float* KmT   = (float*)alloc((size_t)KSTRIDE * KSTRIDE * 4);
  float* u     = (float*)alloc(1024 * 4);
  float* v     = (float*)alloc(1024 * 4);
  int* ibuf    = (int*)alloc(256 * 4);

  prep_all<<<dim3(1 + 3907 + 4536 + 12288), 256, 0, stream>>>(
      target, cnt, offs, rank, clss, ibuf,
      S, Wt, Wthi, Wtlo, Ws, Wshi, Wslo, w_t, wthi, wtlo, w_s, wshi, wslo,
      feat_t, ftb, feat_s, fsb);

  gemm_stage2<<<dim3(640), 512, 0, stream>>>(
      wthi, wtlo, Wthi, Wtlo, wtp, wshi, wslo, Wshi, Wslo, wsp,
      ftb, ftg, fsb, fsg, rank);

  norms_all<<<dim3(1000 + 2000 + 1024), 256, 0, stream>>>(
      ftg, fsg, ftns, fsns, ftns2, fsns2, offs, cnt, s_tt, s_ss,
      wtp, wsp, wtn, wsn, wtphi, wtplo, wsphi, wsplo);

  cw_sts<<<dim3(256 + 4096), 256, 0, stream>>>(
      wtphi, wtplo, wsphi, wsplo, Cm, wtn, wsn,
      ftg, fsg, clss, ftns, fsns, ftns2, fsns2, S);

  combine<<<dim3(16 * 16), 256, 0, stream>>>(Cm, s_tt, s_ss, S, cnt, Km, KmT);

  sinkhorn7<<<dim3(GBLK), 256, 0, stream>>>(Km, KmT, Cm, u, v, ibuf, out);
}

// Round 14
// 457.336 us; speedup vs baseline: 1.1118x; 1.1118x over previous
//
#include <hip/hip_runtime.h>

#define NCLS 1000
#define NB 4096
#define PD 512
#define GBLK 63
#define KSTRIDE 1024

typedef __attribute__((ext_vector_type(8))) short bf16x8;
typedef __attribute__((ext_vector_type(4))) float f32x4;
typedef __attribute__((ext_vector_type(16))) float f32x16;

__device__ __forceinline__ ushort f2bf(float x) {
  union { float f; unsigned u; } c; c.f = x;
  unsigned r = c.u + 0x7FFFu + ((c.u >> 16) & 1u);
  return (ushort)(r >> 16);
}
__device__ __forceinline__ float bf2f(ushort h) {
  union { unsigned u; float f; } c; c.u = ((unsigned)h) << 16; return c.f;
}

// ================= prep_all: classprep(b0) | zero S | weight splits | feat conv =================
__global__ __launch_bounds__(256) void prep_all(
    const int* __restrict__ target, int* __restrict__ cnt_g, int* __restrict__ offs_g,
    int* __restrict__ rank, int* __restrict__ clss, int* __restrict__ ibuf,
    float* __restrict__ S,
    const float* __restrict__ Wt, ushort* __restrict__ Wthi, ushort* __restrict__ Wtlo,
    const float* __restrict__ Ws, ushort* __restrict__ Wshi, ushort* __restrict__ Wslo,
    const float* __restrict__ wt, ushort* __restrict__ wthi, ushort* __restrict__ wtlo,
    const float* __restrict__ ws, ushort* __restrict__ wshi, ushort* __restrict__ wslo,
    const float* __restrict__ ft, ushort* __restrict__ ftb,
    const float* __restrict__ fs, ushort* __restrict__ fsb) {
  int b = blockIdx.x;
  int t = threadIdx.x;
  if (b == 0) {
    __shared__ int cnt_s[1024];
    __shared__ int tsum[256];
    for (int i = t; i < 1024; i += 256) cnt_s[i] = 0;
    ibuf[t] = 0;
    __syncthreads();
    int tg[16];
#pragma unroll
    for (int q = 0; q < 16; ++q) {
      tg[q] = target[t + 256 * q];
      atomicAdd(&cnt_s[tg[q]], 1);
    }
    __syncthreads();
    int c0 = cnt_s[4 * t], c1 = cnt_s[4 * t + 1], c2 = cnt_s[4 * t + 2], c3 = cnt_s[4 * t + 3];
    int local = c0 + c1 + c2 + c3;
    tsum[t] = local;
    __syncthreads();
    for (int d = 1; d < 256; d <<= 1) {
      int v2 = (t >= d) ? tsum[t - d] : 0;
      __syncthreads();
      tsum[t] += v2;
      __syncthreads();
    }
    int base = tsum[t] - local;
    int o0 = base, o1 = base + c0, o2 = o1 + c1, o3 = o2 + c2;
    if (4 * t < NCLS)     { cnt_g[4 * t] = c0;     offs_g[4 * t] = o0; }
    if (4 * t + 1 < NCLS) { cnt_g[4 * t + 1] = c1; offs_g[4 * t + 1] = o1; }
    if (4 * t + 2 < NCLS) { cnt_g[4 * t + 2] = c2; offs_g[4 * t + 2] = o2; }
    if (4 * t + 3 < NCLS) { cnt_g[4 * t + 3] = c3; offs_g[4 * t + 3] = o3; }
    cnt_s[4 * t] = o0; cnt_s[4 * t + 1] = o1; cnt_s[4 * t + 2] = o2; cnt_s[4 * t + 3] = o3;
    __syncthreads();
#pragma unroll
    for (int q = 0; q < 16; ++q) {
      int i = t + 256 * q;
      int pos = atomicAdd(&cnt_s[tg[q]], 1);
      rank[i] = pos;
      clss[pos] = tg[q];
    }
    return;
  }
  if (b < 3908) {
    int i = (b - 1) * 256 + t;
    if (i < NCLS * NCLS) S[i] = 0.f;
    return;
  }
  if (b >= 8444) {
    int idx = (b - 8444) * 256 + t;
    const float* src; ushort* dst;
    if (idx < 2097152) { src = ft; dst = ftb; }
    else { idx -= 2097152; src = fs; dst = fsb; }
    float4 v = reinterpret_cast<const float4*>(src)[idx];
    ushort4 h;
    h.x = f2bf(v.x); h.y = f2bf(v.y); h.z = f2bf(v.z); h.w = f2bf(v.w);
    reinterpret_cast<ushort4*>(dst)[idx] = h;
    return;
  }
  int idx = (b - 3908) * 256 + t;
  const float* src; ushort* hi; ushort* lo;
  if (idx < 262144) { src = Wt; hi = Wthi; lo = Wtlo; }
  else {
    idx -= 262144;
    if (idx < 131072) { src = Ws; hi = Wshi; lo = Wslo; }
    else {
      idx -= 131072;
      if (idx < 512000) { src = wt; hi = wthi; lo = wtlo; }
      else { idx -= 512000; src = ws; hi = wshi; lo = wslo; }
    }
  }
  float4 v = reinterpret_cast<const float4*>(src)[idx];
  float vv[4] = {v.x, v.y, v.z, v.w};
  ushort h[4], l[4];
#pragma unroll
  for (int j = 0; j < 4; ++j) {
    h[j] = f2bf(vv[j]);
    l[j] = f2bf(vv[j] - bf2f(h[j]));
  }
  ushort4 h4; h4.x = h[0]; h4.y = h[1]; h4.z = h[2]; h4.w = h[3];
  ushort4 l4; l4.x = l[0]; l4.y = l[1]; l4.z = l[2]; l4.w = l[3];
  reinterpret_cast<ushort4*>(hi)[idx] = h4;
  reinterpret_cast<ushort4*>(lo)[idx] = l4;
}

// ---------------- split-bf16 MFMA NT GEMM body (16x16 frags) ----------------
__device__ __forceinline__ void gemm_split_body(
    const ushort* __restrict__ Ahi, const ushort* __restrict__ Alo,
    const ushort* __restrict__ Bhi, const ushort* __restrict__ Blo,
    float* __restrict__ C, int M, int N, int K,
    const float* __restrict__ rn, const float* __restrict__ cn, int mode,
    int m0, int n0) {
  int tid = threadIdx.x;
  int lane = tid & 63, wv = tid >> 6;
  int wi = wv >> 1, wj = wv & 1;
  int rA = m0 + wi * 32, rB = n0 + wj * 32;
  int lr = lane & 15, lk = (lane >> 4) << 3;
  bf16x8 zb = {0, 0, 0, 0, 0, 0, 0, 0};
  f32x4 z4 = {0.f, 0.f, 0.f, 0.f};
  f32x4 acc[2][2];
#pragma unroll
  for (int i = 0; i < 2; ++i)
#pragma unroll
    for (int j = 0; j < 2; ++j) acc[i][j] = z4;
  for (int kb = 0; kb < K; kb += 32) {
    bf16x8 ah[2], al[2], bh[2], bl[2];
#pragma unroll
    for (int f = 0; f < 2; ++f) {
      int ra = rA + f * 16 + lr;
      if (ra < M) {
        size_t o = (size_t)ra * K + kb + lk;
        ah[f] = *reinterpret_cast<const bf16x8*>(Ahi + o);
        al[f] = *reinterpret_cast<const bf16x8*>(Alo + o);
      } else { ah[f] = zb; al[f] = zb; }
      int rb = rB + f * 16 + lr;
      if (rb < N) {
        size_t o = (size_t)rb * K + kb + lk;
        bh[f] = *reinterpret_cast<const bf16x8*>(Bhi + o);
        bl[f] = *reinterpret_cast<const bf16x8*>(Blo + o);
      } else { bh[f] = zb; bl[f] = zb; }
    }
#pragma unroll
    for (int i = 0; i < 2; ++i)
#pragma unroll
      for (int j = 0; j < 2; ++j) {
        acc[i][j] = __builtin_amdgcn_mfma_f32_16x16x32_bf16(ah[i], bh[j], acc[i][j], 0, 0, 0);
        acc[i][j] = __builtin_amdgcn_mfma_f32_16x16x32_bf16(ah[i], bl[j], acc[i][j], 0, 0, 0);
        acc[i][j] = __builtin_amdgcn_mfma_f32_16x16x32_bf16(al[i], bh[j], acc[i][j], 0, 0, 0);
      }
  }
#pragma unroll
  for (int i = 0; i < 2; ++i)
#pragma unroll
    for (int j = 0; j < 2; ++j)
#pragma unroll
      for (int r = 0; r < 4; ++r) {
        int m = rA + i * 16 + ((lane >> 4) << 2) + r;
        int n = rB + j * 16 + lr;
        if (m < M && n < N) {
          float vv = acc[i][j][r];
          if (mode == 1) vv = fmaxf(rn[m] + cn[n] - 2.f * vv, 0.f);
          C[(size_t)m * N + n] = vv;
        }
      }
}

// both weight projections in one launch (z selects) — round-12 proven form
__global__ __launch_bounds__(256) void gemm_splitW(
    const ushort* __restrict__ A0hi, const ushort* __restrict__ A0lo,
    const ushort* __restrict__ B0hi, const ushort* __restrict__ B0lo, float* __restrict__ C0,
    const ushort* __restrict__ A1hi, const ushort* __restrict__ A1lo,
    const ushort* __restrict__ B1hi, const ushort* __restrict__ B1lo, float* __restrict__ C1) {
  int z = blockIdx.z;
  gemm_split_body(z ? A1hi : A0hi, z ? A1lo : A0lo, z ? B1hi : B0hi, z ? B1lo : B0lo,
                  z ? C1 : C0, NCLS, PD, z ? 1024 : 2048, nullptr, nullptr, 0,
                  blockIdx.y * 64, blockIdx.x * 64);
}

// ================= feat GEMMs fused (z), bf16 A; 64x128 tile, 8 waves — round-12 proven =================
__global__ __launch_bounds__(512) void gemm_feat2(
    const ushort* __restrict__ A0, const ushort* __restrict__ B0, ushort* __restrict__ G0,
    const ushort* __restrict__ A1, const ushort* __restrict__ B1, ushort* __restrict__ G1,
    const int* __restrict__ rank) {
  int z = blockIdx.z;
  const ushort* A = z ? A1 : A0;
  const ushort* B = z ? B1 : B0;
  ushort* G = z ? G1 : G0;
  int K = z ? 1024 : 2048;
  __shared__ int rk[64];
  int tid = threadIdx.x;
  int lane = tid & 63, wv = tid >> 6;
  int wi = wv >> 2, wj = wv & 3;
  int m0 = blockIdx.y * 64, n0 = blockIdx.x * 128;
  if (tid < 64) rk[tid] = rank[m0 + tid];
  int lr = lane & 15, lk = (lane >> 4) << 3;
  const ushort* pa0 = A + (size_t)(m0 + wi * 32 + lr) * K + lk;
  const ushort* pa1 = pa0 + (size_t)16 * K;
  const ushort* pb0 = B + (size_t)(n0 + wj * 32 + lr) * K + lk;
  const ushort* pb1 = pb0 + (size_t)16 * K;
  f32x4 z4 = {0.f, 0.f, 0.f, 0.f};
  f32x4 a00 = z4, a01 = z4, a10 = z4, a11 = z4;
#pragma unroll 2
  for (int kb = 0; kb < K; kb += 32) {
    bf16x8 a0 = *reinterpret_cast<const bf16x8*>(pa0 + kb);
    bf16x8 a1 = *reinterpret_cast<const bf16x8*>(pa1 + kb);
    bf16x8 b0 = *reinterpret_cast<const bf16x8*>(pb0 + kb);
    bf16x8 b1 = *reinterpret_cast<const bf16x8*>(pb1 + kb);
    a00 = __builtin_amdgcn_mfma_f32_16x16x32_bf16(a0, b0, a00, 0, 0, 0);
    a01 = __builtin_amdgcn_mfma_f32_16x16x32_bf16(a0, b1, a01, 0, 0, 0);
    a10 = __builtin_amdgcn_mfma_f32_16x16x32_bf16(a1, b0, a10, 0, 0, 0);
    a11 = __builtin_amdgcn_mfma_f32_16x16x32_bf16(a1, b1, a11, 0, 0, 0);
  }
  __syncthreads();
  f32x4 acc[2][2] = {{a00, a01}, {a10, a11}};
#pragma unroll
  for (int i = 0; i < 2; ++i)
#pragma unroll
    for (int j = 0; j < 2; ++j)
#pragma unroll
      for (int r = 0; r < 4; ++r) {
        int rloc = wi * 32 + i * 16 + ((lane >> 4) << 2) + r;
        int n = n0 + wj * 32 + j * 16 + lr;
        G[(size_t)rk[rloc] * PD + n] = f2bf(acc[i][j][r]);
      }
}

// ================= norms_all (256 thr): class pairs | normsplit | bf16 norms =================
__global__ __launch_bounds__(256) void norms_all(
    const ushort* __restrict__ ftg, const ushort* __restrict__ fsg,
    float* __restrict__ ftns, float* __restrict__ fsns,
    float* __restrict__ ftns2, float* __restrict__ fsns2,
    const int* __restrict__ offs, const int* __restrict__ cnt,
    float* __restrict__ s_tt, float* __restrict__ s_ss,
    const float* __restrict__ wtp, const float* __restrict__ wsp,
    float* __restrict__ wtn, float* __restrict__ wsn,
    ushort* __restrict__ wtphi, ushort* __restrict__ wtplo,
    ushort* __restrict__ wsphi, ushort* __restrict__ wsplo) {
  int b = blockIdx.x;
  int lane = threadIdx.x & 63, wave = threadIdx.x >> 6;
  if (b < 1000) {
    int k = b;
    int c = cnt[k];
    if (c == 0) {
      if (threadIdx.x == 0) { s_tt[k] = 0.f; s_ss[k] = 0.f; }
      return;
    }
    int base = offs[k];
    int tot = c * (c - 1);
    float sumt = 0.f, sums = 0.f;
    for (int p = wave; p < tot; p += 4) {
      int i = p / (c - 1), q = p - i * (c - 1);
      int j = q + (q >= i);
      bf16x8 ta = *reinterpret_cast<const bf16x8*>(ftg + (size_t)(base + i) * PD + lane * 8);
      bf16x8 tb = *reinterpret_cast<const bf16x8*>(ftg + (size_t)(base + j) * PD + lane * 8);
      bf16x8 sa = *reinterpret_cast<const bf16x8*>(fsg + (size_t)(base + i) * PD + lane * 8);
      bf16x8 sb = *reinterpret_cast<const bf16x8*>(fsg + (size_t)(base + j) * PD + lane * 8);
      float dt = 0.f, ds = 0.f;
#pragma unroll
      for (int e = 0; e < 8; ++e) {
        float d1 = bf2f((ushort)ta[e]) - bf2f((ushort)tb[e]); dt += d1 * d1;
        float d2 = bf2f((ushort)sa[e]) - bf2f((ushort)sb[e]); ds += d2 * d2;
      }
#pragma unroll
      for (int off = 32; off; off >>= 1) { dt += __shfl_down(dt, off); ds += __shfl_down(ds, off); }
      if (lane == 0) { sumt += __expf(-0.5f * dt); sums += __expf(-0.5f * ds); }
    }
    __shared__ float rt[4], rs[4];
    if (lane == 0) { rt[wave] = sumt; rs[wave] = sums; }
    __syncthreads();
    if (threadIdx.x == 0) {
      s_tt[k] = (float)c + rt[0] + rt[1] + rt[2] + rt[3];
      s_ss[k] = (float)c + rs[0] + rs[1] + rs[2] + rs[3];
    }
    return;
  }
  if (b < 3000) {
    int bb = b - 1000, t = threadIdx.x;
    int row = (bb < NCLS) ? bb : bb - NCLS;
    const float* src = (bb < NCLS) ? wtp : wsp;
    ushort* hi = (bb < NCLS) ? wtphi : wsphi;
    ushort* lo = (bb < NCLS) ? wtplo : wsplo;
    float* nrm = (bb < NCLS) ? wtn : wsn;
    float2 v = reinterpret_cast<const float2*>(src + (size_t)row * PD)[t];
    ushort h0 = f2bf(v.x), h1 = f2bf(v.y);
    ushort l0 = f2bf(v.x - bf2f(h0)), l1 = f2bf(v.y - bf2f(h1));
    ushort2 h2; h2.x = h0; h2.y = h1;
    ushort2 l2; l2.x = l0; l2.y = l1;
    reinterpret_cast<ushort2*>(hi + (size_t)row * PD)[t] = h2;
    reinterpret_cast<ushort2*>(lo + (size_t)row * PD)[t] = l2;
    float s = v.x * v.x + v.y * v.y;
    __shared__ float red[256];
    red[t] = s;
    __syncthreads();
    for (int st = 128; st > 0; st >>= 1) {
      if (t < st) red[t] += red[t + st];
      __syncthreads();
    }
    if (t == 0) nrm[row] = red[0];
    return;
  }
  int r = (b - 3000) * 4 + wave;
  bf16x8 a = *reinterpret_cast<const bf16x8*>(ftg + (size_t)r * PD + lane * 8);
  bf16x8 bb2 = *reinterpret_cast<const bf16x8*>(fsg + (size_t)r * PD + lane * 8);
  float st = 0.f, ss = 0.f;
#pragma unroll
  for (int e = 0; e < 8; ++e) {
    float x = bf2f((ushort)a[e]); st += x * x;
    float y = bf2f((ushort)bb2[e]); ss += y * y;
  }
  float stp = (lane < 16) ? st : 0.f;
  float ssp = (lane < 16) ? ss : 0.f;
#pragma unroll
  for (int off = 32; off; off >>= 1) {
    st += __shfl_down(st, off); ss += __shfl_down(ss, off);
    stp += __shfl_down(stp, off); ssp += __shfl_down(ssp, off);
  }
  if (lane == 0) { ftns[r] = st; fsns[r] = ss; ftns2[r] = stp; fsns2[r] = ssp; }
}

// ================= cw_sts (256 thr): C_weight GEMM | sts_mfma =================
__global__ __launch_bounds__(256) void cw_sts(
    const ushort* __restrict__ wtphi, const ushort* __restrict__ wtplo,
    const ushort* __restrict__ wsphi, const ushort* __restrict__ wsplo,
    float* __restrict__ Cm, const float* __restrict__ wtn, const float* __restrict__ wsn,
    const ushort* __restrict__ ftg, const ushort* __restrict__ fsg,
    const int* __restrict__ clss, const float* __restrict__ ftns,
    const float* __restrict__ fsns, const float* __restrict__ ftns2,
    const float* __restrict__ fsns2, float* __restrict__ S) {
  int b = blockIdx.x;
  int tid = threadIdx.x;
  int lane = tid & 63, wv = tid >> 6;
  if (b < 256) {
    gemm_split_body(wtphi, wtplo, wsphi, wsplo, Cm, NCLS, NCLS, PD,
                    wtn, wsn, 1, (b >> 4) * 64, (b & 15) * 64);
    return;
  }
  int local = b - 256;
  int i0 = (local >> 6) * 64, j0 = (local & 63) * 64;
  __shared__ float tbl[64 * 64];
  __shared__ int rslot[64], cslot[64], rcls[64], ccls[64];
  __shared__ float rns[64], cns[64], prns[64], pcns[64];
  __shared__ int nrs_s, ncs_s;
  int wi = wv >> 1, wj = wv & 1;

  if (tid < 64) {
    int myc = clss[i0 + tid];
    rns[tid] = ftns[i0 + tid]; prns[tid] = ftns2[i0 + tid];
    int flag = (tid > 0) && (myc != clss[i0 + tid - 1]);
    unsigned long long mask = __ballot(flag);
    int slot = __popcll(mask & ((1ull << tid) - 1ull));
    rslot[tid] = slot;
    if (flag || tid == 0) rcls[slot] = myc;
    if (tid == 63) nrs_s = slot + 1;
  } else if (tid < 128) {
    int t = tid - 64;
    int myc = clss[j0 + t];
    cns[t] = fsns[j0 + t]; pcns[t] = fsns2[j0 + t];
    int flag = (t > 0) && (myc != clss[j0 + t - 1]);
    unsigned long long mask = __ballot(flag);
    int slot = __popcll(mask & ((1ull << t) - 1ull));
    cslot[t] = slot;
    if (flag || t == 0) ccls[slot] = myc;
    if (t == 63) ncs_s = slot + 1;
  }
  for (int t = tid; t < 64 * 64; t += 256) tbl[t] = 0.f;
  __syncthreads();

  int r31 = lane & 31, kg = (lane >> 5) << 3;
  const ushort* pa = ftg + (size_t)(i0 + wi * 32 + r31) * PD + kg;
  const ushort* pb = fsg + (size_t)(j0 + wj * 32 + r31) * PD + kg;
  f32x16 acc0, acc1;
#pragma unroll
  for (int r = 0; r < 16; ++r) { acc0[r] = 0.f; acc1[r] = 0.f; }
#pragma unroll
  for (int kb = 0; kb < 128; kb += 32) {
    bf16x8 a0 = *reinterpret_cast<const bf16x8*>(pa + kb);
    bf16x8 b0 = *reinterpret_cast<const bf16x8*>(pb + kb);
    bf16x8 a1 = *reinterpret_cast<const bf16x8*>(pa + kb + 16);
    bf16x8 b1 = *reinterpret_cast<const bf16x8*>(pb + kb + 16);
    acc0 = __builtin_amdgcn_mfma_f32_32x32x16_bf16(a0, b0, acc0, 0, 0, 0);
    acc1 = __builtin_amdgcn_mfma_f32_32x32x16_bf16(a1, b1, acc1, 0, 0, 0);
  }
  int rbase = 4 * (lane >> 5);
  int cloc = wj * 32 + r31;
  float minv = 1e30f;
#pragma unroll
  for (int r = 0; r < 16; ++r) {
    int rloc = wi * 32 + rbase + (r & 3) + 8 * (r >> 2);
    float d = prns[rloc] + pcns[cloc] - 2.f * (acc0[r] + acc1[r]);
    minv = fminf(minv, d);
  }
  bool skip = __all(minv > 300.f);
  if (!skip) {
#pragma unroll
    for (int kb = 128; kb < PD; kb += 32) {
      bf16x8 a0 = *reinterpret_cast<const bf16x8*>(pa + kb);
      bf16x8 b0 = *reinterpret_cast<const bf16x8*>(pb + kb);
      bf16x8 a1 = *reinterpret_cast<const bf16x8*>(pa + kb + 16);
      bf16x8 b1 = *reinterpret_cast<const bf16x8*>(pb + kb + 16);
      acc0 = __builtin_amdgcn_mfma_f32_32x32x16_bf16(a0, b0, acc0, 0, 0, 0);
      acc1 = __builtin_amdgcn_mfma_f32_32x32x16_bf16(a1, b1, acc1, 0, 0, 0);
    }
  }
  __syncthreads();

  if (!skip) {
    int cs = cslot[cloc];
    float run = 0.f;
    int cur = rslot[wi * 32 + rbase];
#pragma unroll
    for (int r = 0; r < 16; ++r) {
      int rloc = wi * 32 + rbase + (r & 3) + 8 * (r >> 2);
      float d = fmaxf(rns[rloc] + cns[cloc] - 2.f * (acc0[r] + acc1[r]), 0.f);
      float e = __expf(-0.5f * d);
      int s = rslot[rloc];
      if (s != cur) {
        if (run != 0.f) atomicAdd(&tbl[cur * 64 + cs], run);
        run = 0.f; cur = s;
      }
      run += e;
    }
    if (run != 0.f) atomicAdd(&tbl[cur * 64 + cs], run);
  }
  __syncthreads();
  int NR = nrs_s, NC = ncs_s;
  for (int t = tid; t < NR * NC; t += 256) {
    int r = t / NC, c2 = t - r * NC;
    float vs = tbl[r * 64 + c2];
    if (vs != 0.f) atomicAdd(&S[(size_t)rcls[r] * NCLS + ccls[c2]], vs);
  }
}

// ================= combine =================
__global__ __launch_bounds__(256) void combine(
    float* __restrict__ C, const float* __restrict__ s_tt,
    const float* __restrict__ s_ss, const float* __restrict__ S,
    const int* __restrict__ cnt, float* __restrict__ Km, float* __restrict__ KmT) {
  __shared__ float tile[64][65];
  int tid = threadIdx.x;
  int k0 = (blockIdx.x >> 4) * 64, l0 = (blockIdx.x & 15) * 64;
  int tx = tid & 63, ty = tid >> 6;
#pragma unroll
  for (int r = 0; r < 16; ++r) {
    int k = k0 + ty * 16 + r, l = l0 + tx;
    float val = 0.f;
    if (k < NCLS && l < NCLS) {
      float cw = C[(size_t)k * NCLS + l];
      int ck = cnt[k], cl = cnt[l];
      float mmd = 0.f;
      if (ck > 0 && cl > 0) {
        float fk = (float)ck, fl = (float)cl;
        mmd = s_tt[k] / (fk * fk) + s_ss[l] / (fl * fl) - 2.f * S[(size_t)k * NCLS + l] / (fk * fl);
      }
      float c = cw - 0.1f * mmd;
      C[(size_t)k * NCLS + l] = c;
      val = __expf(-10.f * c);
    }
    Km[(size_t)k * KSTRIDE + l] = val;
    tile[ty * 16 + r][tx] = val;
  }
  __syncthreads();
#pragma unroll
  for (int r = 0; r < 16; ++r) {
    int l = l0 + ty * 16 + r, k = k0 + tx;
    KmT[(size_t)l * KSTRIDE + k] = tile[tx][ty * 16 + r];
  }
}

// ================= persistent Sinkhorn (round-7 proven) =================
__global__ __launch_bounds__(256, 1) void sinkhorn7(
    const float* __restrict__ Km, const float* __restrict__ KmT,
    const float* __restrict__ C, float* __restrict__ u, float* __restrict__ v,
    int* __restrict__ ibuf, float* __restrict__ out) {
  const int tid = threadIdx.x, bid = blockIdx.x;
  const int lane = tid & 63, wave = tid >> 6;
  const float ab = 1.f / (float)NCLS;
  const int r0 = bid * 16 + wave * 4;
  int* arr = ibuf;
  int* gen8 = ibuf + 128;
  __shared__ int any_s, bflag_s;

  float km[4][16], kt[4][16];
#pragma unroll
  for (int r = 0; r < 4; ++r) {
    const float* pm = Km + (size_t)(r0 + r) * KSTRIDE + lane;
    const float* pt = KmT + (size_t)(r0 + r) * KSTRIDE + lane;
#pragma unroll
    for (int m = 0; m < 16; ++m) { km[r][m] = pm[64 * m]; kt[r][m] = pt[64 * m]; }
  }

  if (bid == 0) {
    for (int i = tid; i < 1024; i += 256) {
      __hip_atomic_store(&u[i], (i < NCLS) ? ab : 0.f, __ATOMIC_RELAXED, __HIP_MEMORY_SCOPE_AGENT);
      __hip_atomic_store(&v[i], 0.f, __ATOMIC_RELAXED, __HIP_MEMORY_SCOPE_AGENT);
    }
    if (tid == 0) __hip_atomic_store(out, 0.f, __ATOMIC_RELAXED, __HIP_MEMORY_SCOPE_AGENT);
  }
  if (tid == 0) { any_s = 0; bflag_s = 0; }

  int ph = 0;
  auto bar = [&](int useflag) -> int {
    __syncthreads();
    ++ph;
    if (tid == 0) {
      int f = useflag ? bflag_s : 0;
      __hip_atomic_store(&arr[bid], (ph << 1) | f, __ATOMIC_RELEASE, __HIP_MEMORY_SCOPE_AGENT);
    }
    if (bid == 0) {
      int f = 0;
      if (tid < GBLK) {
        int val;
        while (((val = __hip_atomic_load(&arr[tid], __ATOMIC_RELAXED, __HIP_MEMORY_SCOPE_AGENT)) >> 1) < ph)
          __builtin_amdgcn_s_sleep(1);
        f = val & 1;
      }
      unsigned long long m = __ballot(f);
      if (tid == 0) any_s = (m != 0ull) ? 1 : 0;
      __syncthreads();
      int a = any_s;
      if (tid < 8)
        __hip_atomic_store(&gen8[tid], (ph << 1) | a, __ATOMIC_RELEASE, __HIP_MEMORY_SCOPE_AGENT);
      return a;
    } else {
      if (tid == 0) {
        int g;
        while (((g = __hip_atomic_load(&gen8[bid & 7], __ATOMIC_RELAXED, __HIP_MEMORY_SCOPE_AGENT)) >> 1) < ph)
          __builtin_amdgcn_s_sleep(1);
        any_s = g & 1;
      }
      __syncthreads();
      return any_s;
    }
  };

  bar(0);

  float up[4], ucur[4], vv[16], s[4];
#pragma unroll
  for (int r = 0; r < 4; ++r) { up[r] = ab; ucur[r] = ab; }

  for (int it = 0; it < 1000; ++it) {
    float uu[16];
#pragma unroll
    for (int m = 0; m < 16; ++m)
      uu[m] = __hip_atomic_load(&u[lane + 64 * m], __ATOMIC_RELAXED, __HIP_MEMORY_SCOPE_AGENT);
#pragma unroll
    for (int r = 0; r < 4; ++r) {
      float acc = 0.f;
#pragma unroll
      for (int m = 0; m < 16; ++m) acc += kt[r][m] * uu[m];
#pragma unroll
      for (int o = 32; o; o >>= 1) acc += __shfl_down(acc, o);
      s[r] = acc;
    }
    if (lane == 0) {
#pragma unroll
      for (int r = 0; r < 4; ++r) {
        float val = (r0 + r < NCLS) ? ab / s[r] : 0.f;
        __hip_atomic_store(&v[r0 + r], val, __ATOMIC_RELAXED, __HIP_MEMORY_SCOPE_AGENT);
      }
    }
    bar(0);

#pragma unroll
    for (int m = 0; m < 16; ++m)
      vv[m] = __hip_atomic_load(&v[lane + 64 * m], __ATOMIC_RELAXED, __HIP_MEMORY_SCOPE_AGENT);
#pragma unroll
    for (int r = 0; r < 4; ++r) {
      float acc = 0.f;
#pragma unroll
      for (int m = 0; m < 16; ++m) acc += km[r][m] * vv[m];
#pragma unroll
      for (int o = 32; o; o >>= 1) acc += __shfl_down(acc, o);
      s[r] = acc;
    }
#pragma unroll
    for (int r = 0; r < 4; ++r) {
      float sv = __shfl(s[r], 0);
      float val = (r0 + r < NCLS) ? ab / sv : 0.f;
      ucur[r] = val;
      if (lane == 0)
        __hip_atomic_store(&u[r0 + r], val, __ATOMIC_RELAXED, __HIP_MEMORY_SCOPE_AGENT);
    }
    int isC = ((it & 7) == 7);
    if (isC) {
      if (lane == 0) {
        bool nc = false;
#pragma unroll
        for (int r = 0; r < 4; ++r)
          if (r0 + r < NCLS && fabsf(ucur[r] - up[r]) > 5e-4f * ucur[r]) nc = true;
        if (nc) bflag_s = 1;
      }
#pragma unroll
      for (int r = 0; r < 4; ++r) up[r] = ucur[r];
    }
    int any = bar(isC);
    if (isC) {
      if (!any) break;
      if (tid == 0) bflag_s = 0;
    }
  }

  float part = 0.f;
#pragma unroll
  for (int r = 0; r < 4; ++r) {
    if (r0 + r < NCLS) {
      const float* cr = C + (size_t)(r0 + r) * NCLS;
      float acc = 0.f;
#pragma unroll
      for (int m = 0; m < 16; ++m)
        acc += km[r][m] * vv[m] * cr[lane + 64 * m];
#pragma unroll
      for (int o = 32; o; o >>= 1) acc += __shfl_down(acc, o);
      if (lane == 0) part += ucur[r] * acc;
    }
  }
  __shared__ float pr[4];
  if (lane == 0) pr[wave] = part;
  __syncthreads();
  if (tid == 0) atomicAdd(out, pr[0] + pr[1] + pr[2] + pr[3]);
}

// ================= host launch =================
extern "C" void kernel_launch(void* const* d_in, const int* in_sizes, int n_in,
                              void* d_out, int out_size, void* d_ws, size_t ws_size,
                              hipStream_t stream) {
  const float* feat_s = (const float*)d_in[0];  // 4096 x 1024
  const float* feat_t = (const float*)d_in[1];  // 4096 x 2048
  const float* w_s = (const float*)d_in[2];     // 1000 x 1024
  const float* w_t = (const float*)d_in[3];     // 1000 x 2048
  const float* Wt = (const float*)d_in[4];      // 512 x 2048
  const float* Ws = (const float*)d_in[5];      // 512 x 1024
  const int* target = (const int*)d_in[6];      // 4096
  float* out = (float*)d_out;

  char* base = (char*)d_ws;
  size_t off = 0;
  auto alloc = [&](size_t bytes) -> void* {
    void* p = base + off;
    off += (bytes + 255) & ~(size_t)255;
    return p;
  };
  ushort* Wthi = (ushort*)alloc((size_t)512 * 2048 * 2);
  ushort* Wtlo = (ushort*)alloc((size_t)512 * 2048 * 2);
  ushort* Wshi = (ushort*)alloc((size_t)512 * 1024 * 2);
  ushort* Wslo = (ushort*)alloc((size_t)512 * 1024 * 2);
  ushort* wthi = (ushort*)alloc((size_t)NCLS * 2048 * 2);
  ushort* wtlo = (ushort*)alloc((size_t)NCLS * 2048 * 2);
  ushort* wshi = (ushort*)alloc((size_t)NCLS * 1024 * 2);
  ushort* wslo = (ushort*)alloc((size_t)NCLS * 1024 * 2);
  ushort* ftb  = (ushort*)alloc((size_t)NB * 2048 * 2);
  ushort* fsb  = (ushort*)alloc((size_t)NB * 1024 * 2);
  float* wtp   = (float*)alloc((size_t)NCLS * PD * 4);
  float* wsp   = (float*)alloc((size_t)NCLS * PD * 4);
  ushort* wtphi = (ushort*)alloc((size_t)NCLS * PD * 2);
  ushort* wtplo = (ushort*)alloc((size_t)NCLS * PD * 2);
  ushort* wsphi = (ushort*)alloc((size_t)NCLS * PD * 2);
  ushort* wsplo = (ushort*)alloc((size_t)NCLS * PD * 2);
  float* wtn   = (float*)alloc(NCLS * 4);
  float* wsn   = (float*)alloc(NCLS * 4);
  ushort* ftg  = (ushort*)alloc((size_t)NB * PD * 2);
  ushort* fsg  = (ushort*)alloc((size_t)NB * PD * 2);
  float* ftns  = (float*)alloc(NB * 4);
  float* fsns  = (float*)alloc(NB * 4);
  float* ftns2 = (float*)alloc(NB * 4);
  float* fsns2 = (float*)alloc(NB * 4);
  int* cnt     = (int*)alloc(NCLS * 4);
  int* offs    = (int*)alloc(NCLS * 4);
  int* rank    = (int*)alloc(NB * 4);
  int* clss    = (int*)alloc(NB * 4);
  float* s_tt  = (float*)alloc(NCLS * 4);
  float* s_ss  = (float*)alloc(NCLS * 4);
  float* S     = (float*)alloc((size_t)NCLS * NCLS * 4);
  float* Cm    = (float*)alloc((size_t)NCLS * NCLS * 4);
  float* Km    = (float*)alloc((size_t)KSTRIDE * KSTRIDE * 4);
  float* KmT   = (float*)alloc((size_t)KSTRIDE * KSTRIDE * 4);
  float* u     = (float*)alloc(1024 * 4);
  float* v     = (float*)alloc(1024 * 4);
  int* ibuf    = (int*)alloc(256 * 4);

  prep_all<<<dim3(1 + 3907 + 4536 + 12288), 256, 0, stream>>>(
      target, cnt, offs, rank, clss, ibuf,
      S, Wt, Wthi, Wtlo, Ws, Wshi, Wslo, w_t, wthi, wtlo, w_s, wshi, wslo,
      feat_t, ftb, feat_s, fsb);

  gemm_splitW<<<dim3(PD / 64, 16, 2), 256, 0, stream>>>(
      wthi, wtlo, Wthi, Wtlo, wtp, wshi, wslo, Wshi, Wslo, wsp);

  gemm_feat2<<<dim3(PD / 128, NB / 64, 2), 512, 0, stream>>>(
      ftb, Wthi, ftg, fsb, Wshi, fsg, rank);

  norms_all<<<dim3(1000 + 2000 + 1024), 256, 0, stream>>>(
      ftg, fsg, ftns, fsns, ftns2, fsns2, offs, cnt, s_tt, s_ss,
      wtp, wsp, wtn, wsn, wtphi, wtplo, wsphi, wsplo);

  cw_sts<<<dim3(256 + 4096), 256, 0, stream>>>(
      wtphi, wtplo, wsphi, wsplo, Cm, wtn, wsn,
      ftg, fsg, clss, ftns, fsns, ftns2, fsns2, S);

  combine<<<dim3(16 * 16), 256, 0, stream>>>(Cm, s_tt, s_ss, S, cnt, Km, KmT);

  sinkhorn7<<<dim3(GBLK), 256, 0, stream>>>(Km, KmT, Cm, u, v, ibuf, out);
}

// Round 15
// 421.866 us; speedup vs baseline: 1.2052x; 1.0841x over previous
//
#include <hip/hip_runtime.h>

#define NCLS 1000
#define NB 4096
#define PD 512
#define GBLK 63
#define KSTRIDE 1024

typedef __attribute__((ext_vector_type(8))) short bf16x8;
typedef __attribute__((ext_vector_type(4))) float f32x4;
typedef __attribute__((ext_vector_type(16))) float f32x16;

__device__ __forceinline__ ushort f2bf(float x) {
  union { float f; unsigned u; } c; c.f = x;
  unsigned r = c.u + 0x7FFFu + ((c.u >> 16) & 1u);
  return (ushort)(r >> 16);
}
__device__ __forceinline__ float bf2f(ushort h) {
  union { unsigned u; float f; } c; c.u = ((unsigned)h) << 16; return c.f;
}

// ================= prep_all: classprep(b0) | zero S | weight splits | feat conv =================
__global__ __launch_bounds__(256) void prep_all(
    const int* __restrict__ target, int* __restrict__ cnt_g, int* __restrict__ offs_g,
    int* __restrict__ rank, int* __restrict__ clss, int* __restrict__ ibuf,
    float* __restrict__ S,
    const float* __restrict__ Wt, ushort* __restrict__ Wthi, ushort* __restrict__ Wtlo,
    const float* __restrict__ Ws, ushort* __restrict__ Wshi, ushort* __restrict__ Wslo,
    const float* __restrict__ wt, ushort* __restrict__ wthi, ushort* __restrict__ wtlo,
    const float* __restrict__ ws, ushort* __restrict__ wshi, ushort* __restrict__ wslo,
    const float* __restrict__ ft, ushort* __restrict__ ftb,
    const float* __restrict__ fs, ushort* __restrict__ fsb) {
  int b = blockIdx.x;
  int t = threadIdx.x;
  if (b == 0) {
    __shared__ int cnt_s[1024];
    __shared__ int tsum[256];
    for (int i = t; i < 1024; i += 256) cnt_s[i] = 0;
    ibuf[t] = 0;
    __syncthreads();
    int tg[16];
#pragma unroll
    for (int q = 0; q < 16; ++q) {
      tg[q] = target[t + 256 * q];
      atomicAdd(&cnt_s[tg[q]], 1);
    }
    __syncthreads();
    int c0 = cnt_s[4 * t], c1 = cnt_s[4 * t + 1], c2 = cnt_s[4 * t + 2], c3 = cnt_s[4 * t + 3];
    int local = c0 + c1 + c2 + c3;
    tsum[t] = local;
    __syncthreads();
    for (int d = 1; d < 256; d <<= 1) {
      int v2 = (t >= d) ? tsum[t - d] : 0;
      __syncthreads();
      tsum[t] += v2;
      __syncthreads();
    }
    int base = tsum[t] - local;
    int o0 = base, o1 = base + c0, o2 = o1 + c1, o3 = o2 + c2;
    if (4 * t < NCLS)     { cnt_g[4 * t] = c0;     offs_g[4 * t] = o0; }
    if (4 * t + 1 < NCLS) { cnt_g[4 * t + 1] = c1; offs_g[4 * t + 1] = o1; }
    if (4 * t + 2 < NCLS) { cnt_g[4 * t + 2] = c2; offs_g[4 * t + 2] = o2; }
    if (4 * t + 3 < NCLS) { cnt_g[4 * t + 3] = c3; offs_g[4 * t + 3] = o3; }
    cnt_s[4 * t] = o0; cnt_s[4 * t + 1] = o1; cnt_s[4 * t + 2] = o2; cnt_s[4 * t + 3] = o3;
    __syncthreads();
#pragma unroll
    for (int q = 0; q < 16; ++q) {
      int i = t + 256 * q;
      int pos = atomicAdd(&cnt_s[tg[q]], 1);
      rank[i] = pos;
      clss[pos] = tg[q];
    }
    return;
  }
  if (b < 3908) {
    int i = (b - 1) * 256 + t;
    if (i < NCLS * NCLS) S[i] = 0.f;
    return;
  }
  if (b >= 8444) {
    int idx = (b - 8444) * 256 + t;
    const float* src; ushort* dst;
    if (idx < 2097152) { src = ft; dst = ftb; }
    else { idx -= 2097152; src = fs; dst = fsb; }
    float4 v = reinterpret_cast<const float4*>(src)[idx];
    ushort4 h;
    h.x = f2bf(v.x); h.y = f2bf(v.y); h.z = f2bf(v.z); h.w = f2bf(v.w);
    reinterpret_cast<ushort4*>(dst)[idx] = h;
    return;
  }
  int idx = (b - 3908) * 256 + t;
  const float* src; ushort* hi; ushort* lo;
  if (idx < 262144) { src = Wt; hi = Wthi; lo = Wtlo; }
  else {
    idx -= 262144;
    if (idx < 131072) { src = Ws; hi = Wshi; lo = Wslo; }
    else {
      idx -= 131072;
      if (idx < 512000) { src = wt; hi = wthi; lo = wtlo; }
      else { idx -= 512000; src = ws; hi = wshi; lo = wslo; }
    }
  }
  float4 v = reinterpret_cast<const float4*>(src)[idx];
  float vv[4] = {v.x, v.y, v.z, v.w};
  ushort h[4], l[4];
#pragma unroll
  for (int j = 0; j < 4; ++j) {
    h[j] = f2bf(vv[j]);
    l[j] = f2bf(vv[j] - bf2f(h[j]));
  }
  ushort4 h4; h4.x = h[0]; h4.y = h[1]; h4.z = h[2]; h4.w = h[3];
  ushort4 l4; l4.x = l[0]; l4.y = l[1]; l4.z = l[2]; l4.w = l[3];
  reinterpret_cast<ushort4*>(hi)[idx] = h4;
  reinterpret_cast<ushort4*>(lo)[idx] = l4;
}

// ---------------- split-bf16 MFMA NT GEMM body (16x16 frags) ----------------
__device__ __forceinline__ void gemm_split_body(
    const ushort* __restrict__ Ahi, const ushort* __restrict__ Alo,
    const ushort* __restrict__ Bhi, const ushort* __restrict__ Blo,
    float* __restrict__ C, int M, int N, int K,
    const float* __restrict__ rn, const float* __restrict__ cn, int mode,
    int m0, int n0) {
  int tid = threadIdx.x;
  int lane = tid & 63, wv = tid >> 6;
  int wi = wv >> 1, wj = wv & 1;
  int rA = m0 + wi * 32, rB = n0 + wj * 32;
  int lr = lane & 15, lk = (lane >> 4) << 3;
  bf16x8 zb = {0, 0, 0, 0, 0, 0, 0, 0};
  f32x4 z4 = {0.f, 0.f, 0.f, 0.f};
  f32x4 acc[2][2];
#pragma unroll
  for (int i = 0; i < 2; ++i)
#pragma unroll
    for (int j = 0; j < 2; ++j) acc[i][j] = z4;
  for (int kb = 0; kb < K; kb += 32) {
    bf16x8 ah[2], al[2], bh[2], bl[2];
#pragma unroll
    for (int f = 0; f < 2; ++f) {
      int ra = rA + f * 16 + lr;
      if (ra < M) {
        size_t o = (size_t)ra * K + kb + lk;
        ah[f] = *reinterpret_cast<const bf16x8*>(Ahi + o);
        al[f] = *reinterpret_cast<const bf16x8*>(Alo + o);
      } else { ah[f] = zb; al[f] = zb; }
      int rb = rB + f * 16 + lr;
      if (rb < N) {
        size_t o = (size_t)rb * K + kb + lk;
        bh[f] = *reinterpret_cast<const bf16x8*>(Bhi + o);
        bl[f] = *reinterpret_cast<const bf16x8*>(Blo + o);
      } else { bh[f] = zb; bl[f] = zb; }
    }
#pragma unroll
    for (int i = 0; i < 2; ++i)
#pragma unroll
      for (int j = 0; j < 2; ++j) {
        acc[i][j] = __builtin_amdgcn_mfma_f32_16x16x32_bf16(ah[i], bh[j], acc[i][j], 0, 0, 0);
        acc[i][j] = __builtin_amdgcn_mfma_f32_16x16x32_bf16(ah[i], bl[j], acc[i][j], 0, 0, 0);
        acc[i][j] = __builtin_amdgcn_mfma_f32_16x16x32_bf16(al[i], bh[j], acc[i][j], 0, 0, 0);
      }
  }
#pragma unroll
  for (int i = 0; i < 2; ++i)
#pragma unroll
    for (int j = 0; j < 2; ++j)
#pragma unroll
      for (int r = 0; r < 4; ++r) {
        int m = rA + i * 16 + ((lane >> 4) << 2) + r;
        int n = rB + j * 16 + lr;
        if (m < M && n < N) {
          float vv = acc[i][j][r];
          if (mode == 1) vv = fmaxf(rn[m] + cn[n] - 2.f * vv, 0.f);
          C[(size_t)m * N + n] = vv;
        }
      }
}

// both weight projections in one launch (z selects)
__global__ __launch_bounds__(256) void gemm_splitW(
    const ushort* __restrict__ A0hi, const ushort* __restrict__ A0lo,
    const ushort* __restrict__ B0hi, const ushort* __restrict__ B0lo, float* __restrict__ C0,
    const ushort* __restrict__ A1hi, const ushort* __restrict__ A1lo,
    const ushort* __restrict__ B1hi, const ushort* __restrict__ B1lo, float* __restrict__ C1) {
  int z = blockIdx.z;
  gemm_split_body(z ? A1hi : A0hi, z ? A1lo : A0lo, z ? B1hi : B0hi, z ? B1lo : B0lo,
                  z ? C1 : C0, NCLS, PD, z ? 1024 : 2048, nullptr, nullptr, 0,
                  blockIdx.y * 64, blockIdx.x * 64);
}

// ================= feat GEMMs fused (z), bf16 A; 64x128 tile, 8 waves =================
__global__ __launch_bounds__(512) void gemm_feat2(
    const ushort* __restrict__ A0, const ushort* __restrict__ B0, ushort* __restrict__ G0,
    const ushort* __restrict__ A1, const ushort* __restrict__ B1, ushort* __restrict__ G1,
    const int* __restrict__ rank) {
  int z = blockIdx.z;
  const ushort* A = z ? A1 : A0;
  const ushort* B = z ? B1 : B0;
  ushort* G = z ? G1 : G0;
  int K = z ? 1024 : 2048;
  __shared__ int rk[64];
  int tid = threadIdx.x;
  int lane = tid & 63, wv = tid >> 6;
  int wi = wv >> 2, wj = wv & 3;
  int m0 = blockIdx.y * 64, n0 = blockIdx.x * 128;
  if (tid < 64) rk[tid] = rank[m0 + tid];
  int lr = lane & 15, lk = (lane >> 4) << 3;
  const ushort* pa0 = A + (size_t)(m0 + wi * 32 + lr) * K + lk;
  const ushort* pa1 = pa0 + (size_t)16 * K;
  const ushort* pb0 = B + (size_t)(n0 + wj * 32 + lr) * K + lk;
  const ushort* pb1 = pb0 + (size_t)16 * K;
  f32x4 z4 = {0.f, 0.f, 0.f, 0.f};
  f32x4 a00 = z4, a01 = z4, a10 = z4, a11 = z4;
#pragma unroll 2
  for (int kb = 0; kb < K; kb += 32) {
    bf16x8 a0 = *reinterpret_cast<const bf16x8*>(pa0 + kb);
    bf16x8 a1 = *reinterpret_cast<const bf16x8*>(pa1 + kb);
    bf16x8 b0 = *reinterpret_cast<const bf16x8*>(pb0 + kb);
    bf16x8 b1 = *reinterpret_cast<const bf16x8*>(pb1 + kb);
    a00 = __builtin_amdgcn_mfma_f32_16x16x32_bf16(a0, b0, a00, 0, 0, 0);
    a01 = __builtin_amdgcn_mfma_f32_16x16x32_bf16(a0, b1, a01, 0, 0, 0);
    a10 = __builtin_amdgcn_mfma_f32_16x16x32_bf16(a1, b0, a10, 0, 0, 0);
    a11 = __builtin_amdgcn_mfma_f32_16x16x32_bf16(a1, b1, a11, 0, 0, 0);
  }
  __syncthreads();
  f32x4 acc[2][2] = {{a00, a01}, {a10, a11}};
#pragma unroll
  for (int i = 0; i < 2; ++i)
#pragma unroll
    for (int j = 0; j < 2; ++j)
#pragma unroll
      for (int r = 0; r < 4; ++r) {
        int rloc = wi * 32 + i * 16 + ((lane >> 4) << 2) + r;
        int n = n0 + wj * 32 + j * 16 + lr;
        G[(size_t)rk[rloc] * PD + n] = f2bf(acc[i][j][r]);
      }
}

// ================= norms_all: class pairs | normsplit | bf16 norms (full + TAIL) =================
// ftns2/fsns2 now hold sqrt(tail norm^2) over dims 128..511.
__global__ __launch_bounds__(256) void norms_all(
    const ushort* __restrict__ ftg, const ushort* __restrict__ fsg,
    float* __restrict__ ftns, float* __restrict__ fsns,
    float* __restrict__ ftns2, float* __restrict__ fsns2,
    const int* __restrict__ offs, const int* __restrict__ cnt,
    float* __restrict__ s_tt, float* __restrict__ s_ss,
    const float* __restrict__ wtp, const float* __restrict__ wsp,
    float* __restrict__ wtn, float* __restrict__ wsn,
    ushort* __restrict__ wtphi, ushort* __restrict__ wtplo,
    ushort* __restrict__ wsphi, ushort* __restrict__ wsplo) {
  int b = blockIdx.x;
  int lane = threadIdx.x & 63, wave = threadIdx.x >> 6;
  if (b < 1000) {
    int k = b;
    int c = cnt[k];
    if (c == 0) {
      if (threadIdx.x == 0) { s_tt[k] = 0.f; s_ss[k] = 0.f; }
      return;
    }
    int base = offs[k];
    int tot = c * (c - 1);
    float sumt = 0.f, sums = 0.f;
    for (int p = wave; p < tot; p += 4) {
      int i = p / (c - 1), q = p - i * (c - 1);
      int j = q + (q >= i);
      bf16x8 ta = *reinterpret_cast<const bf16x8*>(ftg + (size_t)(base + i) * PD + lane * 8);
      bf16x8 tb = *reinterpret_cast<const bf16x8*>(ftg + (size_t)(base + j) * PD + lane * 8);
      bf16x8 sa = *reinterpret_cast<const bf16x8*>(fsg + (size_t)(base + i) * PD + lane * 8);
      bf16x8 sb = *reinterpret_cast<const bf16x8*>(fsg + (size_t)(base + j) * PD + lane * 8);
      float dt = 0.f, ds = 0.f;
#pragma unroll
      for (int e = 0; e < 8; ++e) {
        float d1 = bf2f((ushort)ta[e]) - bf2f((ushort)tb[e]); dt += d1 * d1;
        float d2 = bf2f((ushort)sa[e]) - bf2f((ushort)sb[e]); ds += d2 * d2;
      }
#pragma unroll
      for (int off = 32; off; off >>= 1) { dt += __shfl_down(dt, off); ds += __shfl_down(ds, off); }
      if (lane == 0) { sumt += __expf(-0.5f * dt); sums += __expf(-0.5f * ds); }
    }
    __shared__ float rt[4], rs[4];
    if (lane == 0) { rt[wave] = sumt; rs[wave] = sums; }
    __syncthreads();
    if (threadIdx.x == 0) {
      s_tt[k] = (float)c + rt[0] + rt[1] + rt[2] + rt[3];
      s_ss[k] = (float)c + rs[0] + rs[1] + rs[2] + rs[3];
    }
    return;
  }
  if (b < 3000) {
    int bb = b - 1000, t = threadIdx.x;
    int row = (bb < NCLS) ? bb : bb - NCLS;
    const float* src = (bb < NCLS) ? wtp : wsp;
    ushort* hi = (bb < NCLS) ? wtphi : wsphi;
    ushort* lo = (bb < NCLS) ? wtplo : wsplo;
    float* nrm = (bb < NCLS) ? wtn : wsn;
    float2 v = reinterpret_cast<const float2*>(src + (size_t)row * PD)[t];
    ushort h0 = f2bf(v.x), h1 = f2bf(v.y);
    ushort l0 = f2bf(v.x - bf2f(h0)), l1 = f2bf(v.y - bf2f(h1));
    ushort2 h2; h2.x = h0; h2.y = h1;
    ushort2 l2; l2.x = l0; l2.y = l1;
    reinterpret_cast<ushort2*>(hi + (size_t)row * PD)[t] = h2;
    reinterpret_cast<ushort2*>(lo + (size_t)row * PD)[t] = l2;
    float s = v.x * v.x + v.y * v.y;
    __shared__ float red[256];
    red[t] = s;
    __syncthreads();
    for (int st = 128; st > 0; st >>= 1) {
      if (t < st) red[t] += red[t + st];
      __syncthreads();
    }
    if (t == 0) nrm[row] = red[0];
    return;
  }
  int r = (b - 3000) * 4 + wave;
  bf16x8 a = *reinterpret_cast<const bf16x8*>(ftg + (size_t)r * PD + lane * 8);
  bf16x8 bb2 = *reinterpret_cast<const bf16x8*>(fsg + (size_t)r * PD + lane * 8);
  float st = 0.f, ss = 0.f;
#pragma unroll
  for (int e = 0; e < 8; ++e) {
    float x = bf2f((ushort)a[e]); st += x * x;
    float y = bf2f((ushort)bb2[e]); ss += y * y;
  }
  float stp = (lane < 16) ? st : 0.f;  // prefix (dims 0..127)
  float ssp = (lane < 16) ? ss : 0.f;
#pragma unroll
  for (int off = 32; off; off >>= 1) {
    st += __shfl_down(st, off); ss += __shfl_down(ss, off);
    stp += __shfl_down(stp, off); ssp += __shfl_down(ssp, off);
  }
  if (lane == 0) {
    ftns[r] = st; fsns[r] = ss;
    ftns2[r] = sqrtf(fmaxf(st - stp, 0.f));   // teacher TAIL norm (dims 128..511)
    fsns2[r] = sqrtf(fmaxf(ss - ssp, 0.f));   // student TAIL norm
  }
}

// ================= cw_sts: C_weight GEMM | sts_mfma with Cauchy-Schwarz screen =================
__global__ __launch_bounds__(256) void cw_sts(
    const ushort* __restrict__ wtphi, const ushort* __restrict__ wtplo,
    const ushort* __restrict__ wsphi, const ushort* __restrict__ wsplo,
    float* __restrict__ Cm, const float* __restrict__ wtn, const float* __restrict__ wsn,
    const ushort* __restrict__ ftg, const ushort* __restrict__ fsg,
    const int* __restrict__ clss, const float* __restrict__ ftns,
    const float* __restrict__ fsns, const float* __restrict__ ftnt,
    const float* __restrict__ fsnt, float* __restrict__ S) {
  int b = blockIdx.x;
  int tid = threadIdx.x;
  int lane = tid & 63, wv = tid >> 6;
  if (b < 256) {
    gemm_split_body(wtphi, wtplo, wsphi, wsplo, Cm, NCLS, NCLS, PD,
                    wtn, wsn, 1, (b >> 4) * 64, (b & 15) * 64);
    return;
  }
  int local = b - 256;
  int i0 = (local >> 6) * 64, j0 = (local & 63) * 64;
  __shared__ float tbl[64 * 64];
  __shared__ int rslot[64], cslot[64], rcls[64], ccls[64];
  __shared__ float rns[64], cns[64], rtn[64], ctn[64];
  __shared__ int nrs_s, ncs_s;
  int wi = wv >> 1, wj = wv & 1;

  if (tid < 64) {
    int myc = clss[i0 + tid];
    rns[tid] = ftns[i0 + tid]; rtn[tid] = ftnt[i0 + tid];
    int flag = (tid > 0) && (myc != clss[i0 + tid - 1]);
    unsigned long long mask = __ballot(flag);
    int slot = __popcll(mask & ((1ull << tid) - 1ull));
    rslot[tid] = slot;
    if (flag || tid == 0) rcls[slot] = myc;
    if (tid == 63) nrs_s = slot + 1;
  } else if (tid < 128) {
    int t = tid - 64;
    int myc = clss[j0 + t];
    cns[t] = fsns[j0 + t]; ctn[t] = fsnt[j0 + t];
    int flag = (t > 0) && (myc != clss[j0 + t - 1]);
    unsigned long long mask = __ballot(flag);
    int slot = __popcll(mask & ((1ull << t) - 1ull));
    cslot[t] = slot;
    if (flag || t == 0) ccls[slot] = myc;
    if (t == 63) ncs_s = slot + 1;
  }
  for (int t = tid; t < 64 * 64; t += 256) tbl[t] = 0.f;
  __syncthreads();

  int r31 = lane & 31, kg = (lane >> 5) << 3;
  const ushort* pa = ftg + (size_t)(i0 + wi * 32 + r31) * PD + kg;
  const ushort* pb = fsg + (size_t)(j0 + wj * 32 + r31) * PD + kg;
  f32x16 acc0, acc1;
#pragma unroll
  for (int r = 0; r < 16; ++r) { acc0[r] = 0.f; acc1[r] = 0.f; }
#pragma unroll
  for (int kb = 0; kb < 128; kb += 32) {
    bf16x8 a0 = *reinterpret_cast<const bf16x8*>(pa + kb);
    bf16x8 b0 = *reinterpret_cast<const bf16x8*>(pb + kb);
    bf16x8 a1 = *reinterpret_cast<const bf16x8*>(pa + kb + 16);
    bf16x8 b1 = *reinterpret_cast<const bf16x8*>(pb + kb + 16);
    acc0 = __builtin_amdgcn_mfma_f32_32x32x16_bf16(a0, b0, acc0, 0, 0, 0);
    acc1 = __builtin_amdgcn_mfma_f32_32x32x16_bf16(a1, b1, acc1, 0, 0, 0);
  }
  int rbase = 4 * (lane >> 5);
  int cloc = wj * 32 + r31;
  // Cauchy-Schwarz lower bound on FULL d^2:
  //   d2 >= ||a||^2 + ||b||^2 - 2*dot_prefix - 2*||a_tail||*||b_tail||
  // If all > 250 (> underflow threshold ~206), the whole subtile is exactly 0.
  float minv = 1e30f;
  float ctv = ctn[cloc], cnv = cns[cloc];
#pragma unroll
  for (int r = 0; r < 16; ++r) {
    int rloc = wi * 32 + rbase + (r & 3) + 8 * (r >> 2);
    float lb = rns[rloc] + cnv - 2.f * (acc0[r] + acc1[r]) - 2.f * rtn[rloc] * ctv;
    minv = fminf(minv, lb);
  }
  bool skip = __all(minv > 250.f);
  if (!skip) {
#pragma unroll
    for (int kb = 128; kb < PD; kb += 32) {
      bf16x8 a0 = *reinterpret_cast<const bf16x8*>(pa + kb);
      bf16x8 b0 = *reinterpret_cast<const bf16x8*>(pb + kb);
      bf16x8 a1 = *reinterpret_cast<const bf16x8*>(pa + kb + 16);
      bf16x8 b1 = *reinterpret_cast<const bf16x8*>(pb + kb + 16);
      acc0 = __builtin_amdgcn_mfma_f32_32x32x16_bf16(a0, b0, acc0, 0, 0, 0);
      acc1 = __builtin_amdgcn_mfma_f32_32x32x16_bf16(a1, b1, acc1, 0, 0, 0);
    }
  }
  __syncthreads();

  if (!skip) {
    int cs = cslot[cloc];
    float run = 0.f;
    int cur = rslot[wi * 32 + rbase];
#pragma unroll
    for (int r = 0; r < 16; ++r) {
      int rloc = wi * 32 + rbase + (r & 3) + 8 * (r >> 2);
      float d = fmaxf(rns[rloc] + cnv - 2.f * (acc0[r] + acc1[r]), 0.f);
      float e = __expf(-0.5f * d);
      int s = rslot[rloc];
      if (s != cur) {
        if (run != 0.f) atomicAdd(&tbl[cur * 64 + cs], run);
        run = 0.f; cur = s;
      }
      run += e;
    }
    if (run != 0.f) atomicAdd(&tbl[cur * 64 + cs], run);
  }
  __syncthreads();
  int NR = nrs_s, NC = ncs_s;
  for (int t = tid; t < NR * NC; t += 256) {
    int r = t / NC, c2 = t - r * NC;
    float vs = tbl[r * 64 + c2];
    if (vs != 0.f) atomicAdd(&S[(size_t)rcls[r] * NCLS + ccls[c2]], vs);
  }
}

// ================= combine =================
__global__ __launch_bounds__(256) void combine(
    float* __restrict__ C, const float* __restrict__ s_tt,
    const float* __restrict__ s_ss, const float* __restrict__ S,
    const int* __restrict__ cnt, float* __restrict__ Km, float* __restrict__ KmT) {
  __shared__ float tile[64][65];
  int tid = threadIdx.x;
  int k0 = (blockIdx.x >> 4) * 64, l0 = (blockIdx.x & 15) * 64;
  int tx = tid & 63, ty = tid >> 6;
#pragma unroll
  for (int r = 0; r < 16; ++r) {
    int k = k0 + ty * 16 + r, l = l0 + tx;
    float val = 0.f;
    if (k < NCLS && l < NCLS) {
      float cw = C[(size_t)k * NCLS + l];
      int ck = cnt[k], cl = cnt[l];
      float mmd = 0.f;
      if (ck > 0 && cl > 0) {
        float fk = (float)ck, fl = (float)cl;
        mmd = s_tt[k] / (fk * fk) + s_ss[l] / (fl * fl) - 2.f * S[(size_t)k * NCLS + l] / (fk * fl);
      }
      float c = cw - 0.1f * mmd;
      C[(size_t)k * NCLS + l] = c;
      val = __expf(-10.f * c);
    }
    Km[(size_t)k * KSTRIDE + l] = val;
    tile[ty * 16 + r][tx] = val;
  }
  __syncthreads();
#pragma unroll
  for (int r = 0; r < 16; ++r) {
    int l = l0 + ty * 16 + r, k = k0 + tx;
    KmT[(size_t)l * KSTRIDE + k] = tile[tx][ty * 16 + r];
  }
}

// ================= persistent Sinkhorn (round-7 proven) =================
__global__ __launch_bounds__(256, 1) void sinkhorn7(
    const float* __restrict__ Km, const float* __restrict__ KmT,
    const float* __restrict__ C, float* __restrict__ u, float* __restrict__ v,
    int* __restrict__ ibuf, float* __restrict__ out) {
  const int tid = threadIdx.x, bid = blockIdx.x;
  const int lane = tid & 63, wave = tid >> 6;
  const float ab = 1.f / (float)NCLS;
  const int r0 = bid * 16 + wave * 4;
  int* arr = ibuf;
  int* gen8 = ibuf + 128;
  __shared__ int any_s, bflag_s;

  float km[4][16], kt[4][16];
#pragma unroll
  for (int r = 0; r < 4; ++r) {
    const float* pm = Km + (size_t)(r0 + r) * KSTRIDE + lane;
    const float* pt = KmT + (size_t)(r0 + r) * KSTRIDE + lane;
#pragma unroll
    for (int m = 0; m < 16; ++m) { km[r][m] = pm[64 * m]; kt[r][m] = pt[64 * m]; }
  }

  if (bid == 0) {
    for (int i = tid; i < 1024; i += 256) {
      __hip_atomic_store(&u[i], (i < NCLS) ? ab : 0.f, __ATOMIC_RELAXED, __HIP_MEMORY_SCOPE_AGENT);
      __hip_atomic_store(&v[i], 0.f, __ATOMIC_RELAXED, __HIP_MEMORY_SCOPE_AGENT);
    }
    if (tid == 0) __hip_atomic_store(out, 0.f, __ATOMIC_RELAXED, __HIP_MEMORY_SCOPE_AGENT);
  }
  if (tid == 0) { any_s = 0; bflag_s = 0; }

  int ph = 0;
  auto bar = [&](int useflag) -> int {
    __syncthreads();
    ++ph;
    if (tid == 0) {
      int f = useflag ? bflag_s : 0;
      __hip_atomic_store(&arr[bid], (ph << 1) | f, __ATOMIC_RELEASE, __HIP_MEMORY_SCOPE_AGENT);
    }
    if (bid == 0) {
      int f = 0;
      if (tid < GBLK) {
        int val;
        while (((val = __hip_atomic_load(&arr[tid], __ATOMIC_RELAXED, __HIP_MEMORY_SCOPE_AGENT)) >> 1) < ph)
          __builtin_amdgcn_s_sleep(1);
        f = val & 1;
      }
      unsigned long long m = __ballot(f);
      if (tid == 0) any_s = (m != 0ull) ? 1 : 0;
      __syncthreads();
      int a = any_s;
      if (tid < 8)
        __hip_atomic_store(&gen8[tid], (ph << 1) | a, __ATOMIC_RELEASE, __HIP_MEMORY_SCOPE_AGENT);
      return a;
    } else {
      if (tid == 0) {
        int g;
        while (((g = __hip_atomic_load(&gen8[bid & 7], __ATOMIC_RELAXED, __HIP_MEMORY_SCOPE_AGENT)) >> 1) < ph)
          __builtin_amdgcn_s_sleep(1);
        any_s = g & 1;
      }
      __syncthreads();
      return any_s;
    }
  };

  bar(0);

  float up[4], ucur[4], vv[16], s[4];
#pragma unroll
  for (int r = 0; r < 4; ++r) { up[r] = ab; ucur[r] = ab; }

  for (int it = 0; it < 1000; ++it) {
    float uu[16];
#pragma unroll
    for (int m = 0; m < 16; ++m)
      uu[m] = __hip_atomic_load(&u[lane + 64 * m], __ATOMIC_RELAXED, __HIP_MEMORY_SCOPE_AGENT);
#pragma unroll
    for (int r = 0; r < 4; ++r) {
      float acc = 0.f;
#pragma unroll
      for (int m = 0; m < 16; ++m) acc += kt[r][m] * uu[m];
#pragma unroll
      for (int o = 32; o; o >>= 1) acc += __shfl_down(acc, o);
      s[r] = acc;
    }
    if (lane == 0) {
#pragma unroll
      for (int r = 0; r < 4; ++r) {
        float val = (r0 + r < NCLS) ? ab / s[r] : 0.f;
        __hip_atomic_store(&v[r0 + r], val, __ATOMIC_RELAXED, __HIP_MEMORY_SCOPE_AGENT);
      }
    }
    bar(0);

#pragma unroll
    for (int m = 0; m < 16; ++m)
      vv[m] = __hip_atomic_load(&v[lane + 64 * m], __ATOMIC_RELAXED, __HIP_MEMORY_SCOPE_AGENT);
#pragma unroll
    for (int r = 0; r < 4; ++r) {
      float acc = 0.f;
#pragma unroll
      for (int m = 0; m < 16; ++m) acc += km[r][m] * vv[m];
#pragma unroll
      for (int o = 32; o; o >>= 1) acc += __shfl_down(acc, o);
      s[r] = acc;
    }
#pragma unroll
    for (int r = 0; r < 4; ++r) {
      float sv = __shfl(s[r], 0);
      float val = (r0 + r < NCLS) ? ab / sv : 0.f;
      ucur[r] = val;
      if (lane == 0)
        __hip_atomic_store(&u[r0 + r], val, __ATOMIC_RELAXED, __HIP_MEMORY_SCOPE_AGENT);
    }
    int isC = ((it & 7) == 7);
    if (isC) {
      if (lane == 0) {
        bool nc = false;
#pragma unroll
        for (int r = 0; r < 4; ++r)
          if (r0 + r < NCLS && fabsf(ucur[r] - up[r]) > 5e-4f * ucur[r]) nc = true;
        if (nc) bflag_s = 1;
      }
#pragma unroll
      for (int r = 0; r < 4; ++r) up[r] = ucur[r];
    }
    int any = bar(isC);
    if (isC) {
      if (!any) break;
      if (tid == 0) bflag_s = 0;
    }
  }

  float part = 0.f;
#pragma unroll
  for (int r = 0; r < 4; ++r) {
    if (r0 + r < NCLS) {
      const float* cr = C + (size_t)(r0 + r) * NCLS;
      float acc = 0.f;
#pragma unroll
      for (int m = 0; m < 16; ++m)
        acc += km[r][m] * vv[m] * cr[lane + 64 * m];
#pragma unroll
      for (int o = 32; o; o >>= 1) acc += __shfl_down(acc, o);
      if (lane == 0) part += ucur[r] * acc;
    }
  }
  __shared__ float pr[4];
  if (lane == 0) pr[wave] = part;
  __syncthreads();
  if (tid == 0) atomicAdd(out, pr[0] + pr[1] + pr[2] + pr[3]);
}

// ================= host launch =================
extern "C" void kernel_launch(void* const* d_in, const int* in_sizes, int n_in,
                              void* d_out, int out_size, void* d_ws, size_t ws_size,
                              hipStream_t stream) {
  const float* feat_s = (const float*)d_in[0];  // 4096 x 1024
  const float* feat_t = (const float*)d_in[1];  // 4096 x 2048
  const float* w_s = (const float*)d_in[2];     // 1000 x 1024
  const float* w_t = (const float*)d_in[3];     // 1000 x 2048
  const float* Wt = (const float*)d_in[4];      // 512 x 2048
  const float* Ws = (const float*)d_in[5];      // 512 x 1024
  const int* target = (const int*)d_in[6];      // 4096
  float* out = (float*)d_out;

  char* base = (char*)d_ws;
  size_t off = 0;
  auto alloc = [&](size_t bytes) -> void* {
    void* p = base + off;
    off += (bytes + 255) & ~(size_t)255;
    return p;
  };
  ushort* Wthi = (ushort*)alloc((size_t)512 * 2048 * 2);
  ushort* Wtlo = (ushort*)alloc((size_t)512 * 2048 * 2);
  ushort* Wshi = (ushort*)alloc((size_t)512 * 1024 * 2);
  ushort* Wslo = (ushort*)alloc((size_t)512 * 1024 * 2);
  ushort* wthi = (ushort*)alloc((size_t)NCLS * 2048 * 2);
  ushort* wtlo = (ushort*)alloc((size_t)NCLS * 2048 * 2);
  ushort* wshi = (ushort*)alloc((size_t)NCLS * 1024 * 2);
  ushort* wslo = (ushort*)alloc((size_t)NCLS * 1024 * 2);
  ushort* ftb  = (ushort*)alloc((size_t)NB * 2048 * 2);
  ushort* fsb  = (ushort*)alloc((size_t)NB * 1024 * 2);
  float* wtp   = (float*)alloc((size_t)NCLS * PD * 4);
  float* wsp   = (float*)alloc((size_t)NCLS * PD * 4);
  ushort* wtphi = (ushort*)alloc((size_t)NCLS * PD * 2);
  ushort* wtplo = (ushort*)alloc((size_t)NCLS * PD * 2);
  ushort* wsphi = (ushort*)alloc((size_t)NCLS * PD * 2);
  ushort* wsplo = (ushort*)alloc((size_t)NCLS * PD * 2);
  float* wtn   = (float*)alloc(NCLS * 4);
  float* wsn   = (float*)alloc(NCLS * 4);
  ushort* ftg  = (ushort*)alloc((size_t)NB * PD * 2);
  ushort* fsg  = (ushort*)alloc((size_t)NB * PD * 2);
  float* ftns  = (float*)alloc(NB * 4);
  float* fsns  = (float*)alloc(NB * 4);
  float* ftns2 = (float*)alloc(NB * 4);
  float* fsns2 = (float*)alloc(NB * 4);
  int* cnt     = (int*)alloc(NCLS * 4);
  int* offs    = (int*)alloc(NCLS * 4);
  int* rank    = (int*)alloc(NB * 4);
  int* clss    = (int*)alloc(NB * 4);
  float* s_tt  = (float*)alloc(NCLS * 4);
  float* s_ss  = (float*)alloc(NCLS * 4);
  float* S     = (float*)alloc((size_t)NCLS * NCLS * 4);
  float* Cm    = (float*)alloc((size_t)NCLS * NCLS * 4);
  float* Km    = (float*)alloc((size_t)KSTRIDE * KSTRIDE * 4);
  float* KmT   = (float*)alloc((size_t)KSTRIDE * KSTRIDE * 4);
  float* u     = (float*)alloc(1024 * 4);
  float* v     = (float*)alloc(1024 * 4);
  int* ibuf    = (int*)alloc(256 * 4);

  prep_all<<<dim3(1 + 3907 + 4536 + 12288), 256, 0, stream>>>(
      target, cnt, offs, rank, clss, ibuf,
      S, Wt, Wthi, Wtlo, Ws, Wshi, Wslo, w_t, wthi, wtlo, w_s, wshi, wslo,
      feat_t, ftb, feat_s, fsb);

  gemm_splitW<<<dim3(PD / 64, 16, 2), 256, 0, stream>>>(
      wthi, wtlo, Wthi, Wtlo, wtp, wshi, wslo, Wshi, Wslo, wsp);

  gemm_feat2<<<dim3(PD / 128, NB / 64, 2), 512, 0, stream>>>(
      ftb, Wthi, ftg, fsb, Wshi, fsg, rank);

  norms_all<<<dim3(1000 + 2000 + 1024), 256, 0, stream>>>(
      ftg, fsg, ftns, fsns, ftns2, fsns2, offs, cnt, s_tt, s_ss,
      wtp, wsp, wtn, wsn, wtphi, wtplo, wsphi, wsplo);

  cw_sts<<<dim3(256 + 4096), 256, 0, stream>>>(
      wtphi, wtplo, wsphi, wsplo, Cm, wtn, wsn,
      ftg, fsg, clss, ftns, fsns, ftns2, fsns2, S);

  combine<<<dim3(16 * 16), 256, 0, stream>>>(Cm, s_tt, s_ss, S, cnt, Km, KmT);

  sinkhorn7<<<dim3(GBLK), 256, 0, stream>>>(Km, KmT, Cm, u, v, ibuf, out);
}